// Round 1
// baseline (869.783 us; speedup 1.0000x reference)
//
#include <hip/hip_runtime.h>
#include <hip/hip_bf16.h>
#include <math.h>

// ---- problem constants (from reference) ----
#define H 768
#define I_DIM 384
#define E_NUM 16
#define G_NUM 4
#define TOPK 4
#define IS_DIM 768
#define SCALE_F 2.5f

// ---- GEMM tiling ----
#define TM 64
#define TN 64
#define TK 16
#define APAD 68   // padded LDS stride for transposed A tile (breaks bank alignment)

// =====================================================================
// Router: 1 wave (64 threads) per token.
// lane = e + 16*chunk : each lane does a 192-element partial dot, then
// shuffle-reduce over chunks. Lane 0 runs the (tiny, E=16) serial top-k
// logic replicating jax.lax.top_k tie-breaking (lowest index wins ties).
// =====================================================================
__global__ __launch_bounds__(64) void router_k(
    const float* __restrict__ X, const float* __restrict__ RW,
    const float* __restrict__ RB, const float* __restrict__ CB,
    int* __restrict__ cnt, int* __restrict__ tok_id, float* __restrict__ tok_w,
    int T)
{
    const int t = blockIdx.x;
    const int lane = threadIdx.x;
    const int e = lane & 15;
    const int chunk = lane >> 4;
    const float* xr = X + (size_t)t * H + chunk * (H / 4);
    const float* wr = RW + (size_t)e * H + chunk * (H / 4);
    float s = 0.f;
#pragma unroll 4
    for (int j = 0; j < H / 4; j += 4) {
        float4 a = *(const float4*)(xr + j);
        float4 b = *(const float4*)(wr + j);
        s += a.x * b.x + a.y * b.y + a.z * b.z + a.w * b.w;
    }
    s += __shfl_xor(s, 16);
    s += __shfl_xor(s, 32);

    __shared__ float sc_s[E_NUM];   // sigmoid scores (used for weights)
    __shared__ float sf_s[E_NUM];   // score + corr_bias (used for selection)
    if (lane < E_NUM) {
        float logit = s + RB[e];
        float score = 1.f / (1.f + expf(-logit));
        sc_s[e] = score;
        sf_s[e] = score + CB[e];
    }
    __syncthreads();

    if (lane == 0) {
        // group scores: sum of top-2 per group of 4
        float gs[G_NUM];
        for (int g = 0; g < G_NUM; ++g) {
            float m1 = -1e30f, m2 = -1e30f;
            for (int j = 0; j < E_NUM / G_NUM; ++j) {
                float v = sf_s[g * (E_NUM / G_NUM) + j];
                if (v > m1) { m2 = m1; m1 = v; }
                else if (v > m2) { m2 = v; }
            }
            gs[g] = m1 + m2;
        }
        // top-2 groups (strict > keeps lowest index on ties, like lax.top_k)
        int g1 = 0;
        for (int g = 1; g < G_NUM; ++g) if (gs[g] > gs[g1]) g1 = g;
        int g2 = -1;
        for (int g = 0; g < G_NUM; ++g) {
            if (g == g1) continue;
            if (g2 < 0 || gs[g] > gs[g2]) g2 = g;
        }
        // mask non-selected groups to 0 (matches jnp.where(mask, sfc, 0))
        float m[E_NUM];
        for (int i = 0; i < E_NUM; ++i) {
            int g = i >> 2;
            m[i] = (g == g1 || g == g2) ? sf_s[i] : 0.f;
        }
        // top-4 experts by masked sfc; weights from raw sigmoid scores
        float wsum = 0.f;
        int sel[TOPK]; float wv[TOPK];
        for (int k = 0; k < TOPK; ++k) {
            int best = 0; float bv = -1e30f;
            for (int i = 0; i < E_NUM; ++i)
                if (m[i] > bv) { bv = m[i]; best = i; }
            m[best] = -2e30f;
            sel[k] = best;
            wv[k] = sc_s[best];
            wsum += wv[k];
        }
        float inv = SCALE_F / (wsum + 1e-20f);
        for (int k = 0; k < TOPK; ++k) {
            int pos = atomicAdd(&cnt[sel[k]], 1);
            tok_id[sel[k] * T + pos] = t;
            tok_w[sel[k] * T + pos] = wv[k] * inv;
        }
    }
}

// exclusive scan over E=16 expert counts -> compact h-buffer offsets
__global__ void scan_k(const int* __restrict__ cnt, int* __restrict__ offs)
{
    if (threadIdx.x == 0) {
        int a = 0;
        for (int e2 = 0; e2 < E_NUM; ++e2) { offs[e2] = a; a += cnt[e2]; }
        offs[E_NUM] = a;
    }
}

// =====================================================================
// Shared expert, stage 1: HS = silu(X@sWg + sbg) * (X@sWu + sbu)
// 64x64 tile, 256 threads, 4x4 micro-tile, TK=16, A stored k-major in LDS.
// =====================================================================
__global__ __launch_bounds__(256) void gateup_shared_k(
    const float* __restrict__ X, const float* __restrict__ Wg,
    const float* __restrict__ bgp, const float* __restrict__ Wu,
    const float* __restrict__ bup, float* __restrict__ HS)
{
    __shared__ float As[TK][APAD];
    __shared__ float Bg[TK][TN];
    __shared__ float Bu[TK][TN];
    const int m0 = blockIdx.x * TM;
    const int n0 = blockIdx.y * TN;
    const int tid = threadIdx.x;
    const int tx = tid & 15, ty = tid >> 4;
    const int ar = tid >> 2, ak = (tid & 3) * 4;
    const int bk = tid >> 4, bn = (tid & 15) * 4;
    float ag[4][4] = {{0.f}}, au[4][4] = {{0.f}};

    for (int k0 = 0; k0 < H; k0 += TK) {
        float4 av = *(const float4*)(X + (size_t)(m0 + ar) * H + k0 + ak);
        float4 gv = *(const float4*)(Wg + (size_t)(k0 + bk) * IS_DIM + n0 + bn);
        float4 uv = *(const float4*)(Wu + (size_t)(k0 + bk) * IS_DIM + n0 + bn);
        __syncthreads();
        As[ak + 0][ar] = av.x; As[ak + 1][ar] = av.y;
        As[ak + 2][ar] = av.z; As[ak + 3][ar] = av.w;
        *(float4*)&Bg[bk][bn] = gv;
        *(float4*)&Bu[bk][bn] = uv;
        __syncthreads();
#pragma unroll
        for (int k = 0; k < TK; ++k) {
            float4 a4 = *(const float4*)&As[k][ty * 4];
            float4 g4 = *(const float4*)&Bg[k][tx * 4];
            float4 u4 = *(const float4*)&Bu[k][tx * 4];
            const float aa[4] = {a4.x, a4.y, a4.z, a4.w};
            const float gg[4] = {g4.x, g4.y, g4.z, g4.w};
            const float uu[4] = {u4.x, u4.y, u4.z, u4.w};
#pragma unroll
            for (int i = 0; i < 4; ++i)
#pragma unroll
                for (int j = 0; j < 4; ++j) {
                    ag[i][j] = fmaf(aa[i], gg[j], ag[i][j]);
                    au[i][j] = fmaf(aa[i], uu[j], au[i][j]);
                }
        }
    }
#pragma unroll
    for (int i = 0; i < 4; ++i) {
        const int mrow = m0 + ty * 4 + i;
        float4 o;
#pragma unroll
        for (int j = 0; j < 4; ++j) {
            const int n = n0 + tx * 4 + j;
            float g = ag[i][j] + bgp[n];
            float u = au[i][j] + bup[n];
            float sv = g / (1.f + expf(-g));
            ((float*)&o)[j] = sv * u;
        }
        *(float4*)(HS + (size_t)mrow * IS_DIM + n0 + tx * 4) = o;
    }
}

// Shared expert, stage 2: OUT = HS @ sWd + sbd  (initializes d_out)
__global__ __launch_bounds__(256) void down_shared_k(
    const float* __restrict__ HS, const float* __restrict__ Wd,
    const float* __restrict__ bdp, float* __restrict__ OUT)
{
    __shared__ float As[TK][APAD];
    __shared__ float Bs[TK][TN];
    const int m0 = blockIdx.x * TM;
    const int n0 = blockIdx.y * TN;
    const int tid = threadIdx.x;
    const int tx = tid & 15, ty = tid >> 4;
    const int ar = tid >> 2, ak = (tid & 3) * 4;
    const int bk = tid >> 4, bn = (tid & 15) * 4;
    float acc[4][4] = {{0.f}};

    for (int k0 = 0; k0 < IS_DIM; k0 += TK) {
        float4 av = *(const float4*)(HS + (size_t)(m0 + ar) * IS_DIM + k0 + ak);
        float4 bv = *(const float4*)(Wd + (size_t)(k0 + bk) * H + n0 + bn);
        __syncthreads();
        As[ak + 0][ar] = av.x; As[ak + 1][ar] = av.y;
        As[ak + 2][ar] = av.z; As[ak + 3][ar] = av.w;
        *(float4*)&Bs[bk][bn] = bv;
        __syncthreads();
#pragma unroll
        for (int k = 0; k < TK; ++k) {
            float4 a4 = *(const float4*)&As[k][ty * 4];
            float4 b4 = *(const float4*)&Bs[k][tx * 4];
            const float aa[4] = {a4.x, a4.y, a4.z, a4.w};
            const float bb[4] = {b4.x, b4.y, b4.z, b4.w};
#pragma unroll
            for (int i = 0; i < 4; ++i)
#pragma unroll
                for (int j = 0; j < 4; ++j)
                    acc[i][j] = fmaf(aa[i], bb[j], acc[i][j]);
        }
    }
#pragma unroll
    for (int i = 0; i < 4; ++i) {
        const int mrow = m0 + ty * 4 + i;
        float4 o;
#pragma unroll
        for (int j = 0; j < 4; ++j)
            ((float*)&o)[j] = acc[i][j] + bdp[n0 + tx * 4 + j];
        *(float4*)(OUT + (size_t)mrow * H + n0 + tx * 4) = o;
    }
}

// =====================================================================
// Routed experts, stage 1: per expert e, gather its tokens and compute
// h = silu(Xg@gWg[e]+gbg[e]) * (Xg@gWu[e]+gbu[e]) into compact HB rows.
// grid = (T/TM, I/TN, E); blocks beyond cnt[e] exit early.
// =====================================================================
__global__ __launch_bounds__(256) void gateup_routed_k(
    const float* __restrict__ X, const float* __restrict__ GWg,
    const float* __restrict__ Gbg, const float* __restrict__ GWu,
    const float* __restrict__ Gbu, const int* __restrict__ cnt,
    const int* __restrict__ offs, const int* __restrict__ tok_id,
    float* __restrict__ HB, int T)
{
    const int e = blockIdx.z;
    const int ne = cnt[e];
    const int m0 = blockIdx.x * TM;
    if (m0 >= ne) return;

    const float* Wg = GWg + (size_t)e * H * I_DIM;
    const float* Wu = GWu + (size_t)e * H * I_DIM;
    const float* bg = Gbg + e * I_DIM;
    const float* bu = Gbu + e * I_DIM;
    const int* tl = tok_id + (size_t)e * T;

    __shared__ float As[TK][APAD];
    __shared__ float Bg[TK][TN];
    __shared__ float Bu[TK][TN];
    const int n0 = blockIdx.y * TN;
    const int tid = threadIdx.x;
    const int tx = tid & 15, ty = tid >> 4;
    const int ar = tid >> 2, ak = (tid & 3) * 4;
    const int bk = tid >> 4, bn = (tid & 15) * 4;

    const int arow = min(m0 + ar, ne - 1);   // clamp for partial tiles
    const int tok = tl[arow];
    const float* xrow = X + (size_t)tok * H;

    float ag[4][4] = {{0.f}}, au[4][4] = {{0.f}};
    for (int k0 = 0; k0 < H; k0 += TK) {
        float4 av = *(const float4*)(xrow + k0 + ak);
        float4 gv = *(const float4*)(Wg + (size_t)(k0 + bk) * I_DIM + n0 + bn);
        float4 uv = *(const float4*)(Wu + (size_t)(k0 + bk) * I_DIM + n0 + bn);
        __syncthreads();
        As[ak + 0][ar] = av.x; As[ak + 1][ar] = av.y;
        As[ak + 2][ar] = av.z; As[ak + 3][ar] = av.w;
        *(float4*)&Bg[bk][bn] = gv;
        *(float4*)&Bu[bk][bn] = uv;
        __syncthreads();
#pragma unroll
        for (int k = 0; k < TK; ++k) {
            float4 a4 = *(const float4*)&As[k][ty * 4];
            float4 g4 = *(const float4*)&Bg[k][tx * 4];
            float4 u4 = *(const float4*)&Bu[k][tx * 4];
            const float aa[4] = {a4.x, a4.y, a4.z, a4.w};
            const float gg[4] = {g4.x, g4.y, g4.z, g4.w};
            const float uu[4] = {u4.x, u4.y, u4.z, u4.w};
#pragma unroll
            for (int i = 0; i < 4; ++i)
#pragma unroll
                for (int j = 0; j < 4; ++j) {
                    ag[i][j] = fmaf(aa[i], gg[j], ag[i][j]);
                    au[i][j] = fmaf(aa[i], uu[j], au[i][j]);
                }
        }
    }
    const int base = offs[e];
#pragma unroll
    for (int i = 0; i < 4; ++i) {
        const int row = m0 + ty * 4 + i;
        if (row < ne) {
            float4 o;
#pragma unroll
            for (int j = 0; j < 4; ++j) {
                const int n = n0 + tx * 4 + j;
                float g = ag[i][j] + bg[n];
                float u = au[i][j] + bu[n];
                float sv = g / (1.f + expf(-g));
                ((float*)&o)[j] = sv * u;
            }
            *(float4*)(HB + (size_t)(base + row) * I_DIM + n0 + tx * 4) = o;
        }
    }
}

// Routed experts, stage 2: out[tok] += w * (h @ gWd[e] + gbd[e]) via atomics.
// Runs after down_shared_k initialized OUT (same stream => ordered).
__global__ __launch_bounds__(256) void down_routed_k(
    const float* __restrict__ HB, const float* __restrict__ GWd,
    const float* __restrict__ Gbd, const int* __restrict__ cnt,
    const int* __restrict__ offs, const int* __restrict__ tok_id,
    const float* __restrict__ tok_w, float* __restrict__ OUT, int T)
{
    const int e = blockIdx.z;
    const int ne = cnt[e];
    const int m0 = blockIdx.x * TM;
    if (m0 >= ne) return;

    const float* Wd = GWd + (size_t)e * I_DIM * H;
    const float* bd = Gbd + (size_t)e * H;
    const int base = offs[e];

    __shared__ float As[TK][APAD];
    __shared__ float Bs[TK][TN];
    const int n0 = blockIdx.y * TN;
    const int tid = threadIdx.x;
    const int tx = tid & 15, ty = tid >> 4;
    const int ar = tid >> 2, ak = (tid & 3) * 4;
    const int bk = tid >> 4, bn = (tid & 15) * 4;

    const int arow = min(m0 + ar, ne - 1);
    const float* hrow = HB + (size_t)(base + arow) * I_DIM;

    float acc[4][4] = {{0.f}};
    for (int k0 = 0; k0 < I_DIM; k0 += TK) {
        float4 av = *(const float4*)(hrow + k0 + ak);
        float4 bv = *(const float4*)(Wd + (size_t)(k0 + bk) * H + n0 + bn);
        __syncthreads();
        As[ak + 0][ar] = av.x; As[ak + 1][ar] = av.y;
        As[ak + 2][ar] = av.z; As[ak + 3][ar] = av.w;
        *(float4*)&Bs[bk][bn] = bv;
        __syncthreads();
#pragma unroll
        for (int k = 0; k < TK; ++k) {
            float4 a4 = *(const float4*)&As[k][ty * 4];
            float4 b4 = *(const float4*)&Bs[k][tx * 4];
            const float aa[4] = {a4.x, a4.y, a4.z, a4.w};
            const float bb[4] = {b4.x, b4.y, b4.z, b4.w};
#pragma unroll
            for (int i = 0; i < 4; ++i)
#pragma unroll
                for (int j = 0; j < 4; ++j)
                    acc[i][j] = fmaf(aa[i], bb[j], acc[i][j]);
        }
    }
#pragma unroll
    for (int i = 0; i < 4; ++i) {
        const int row = m0 + ty * 4 + i;
        if (row < ne) {
            const int tok = tok_id[(size_t)e * T + row];
            const float w = tok_w[(size_t)e * T + row];
#pragma unroll
            for (int j = 0; j < 4; ++j) {
                const int n = n0 + tx * 4 + j;
                atomicAdd(&OUT[(size_t)tok * H + n], w * (acc[i][j] + bd[n]));
            }
        }
    }
}

extern "C" void kernel_launch(void* const* d_in, const int* in_sizes, int n_in,
                              void* d_out, int out_size, void* d_ws, size_t ws_size,
                              hipStream_t stream)
{
    const float* X   = (const float*)d_in[0];
    const float* RW  = (const float*)d_in[1];
    const float* RB  = (const float*)d_in[2];
    const float* CB  = (const float*)d_in[3];
    const float* GWg = (const float*)d_in[4];
    const float* Gbg = (const float*)d_in[5];
    const float* GWu = (const float*)d_in[6];
    const float* Gbu = (const float*)d_in[7];
    const float* GWd = (const float*)d_in[8];
    const float* Gbd = (const float*)d_in[9];
    const float* SWg = (const float*)d_in[10];
    const float* Sbg = (const float*)d_in[11];
    const float* SWu = (const float*)d_in[12];
    const float* Sbu = (const float*)d_in[13];
    const float* SWd = (const float*)d_in[14];
    const float* Sbd = (const float*)d_in[15];
    float* OUT = (float*)d_out;
    const int T = in_sizes[0] / H;   // 2048

    // workspace carve-up (all 256B-aligned)
    char* w = (char*)d_ws;
    int* cnt    = (int*)w;   w += 256;
    int* offs   = (int*)w;   w += 256;
    int* tok_id = (int*)w;   w += (size_t)E_NUM * T * sizeof(int);
    float* tok_w = (float*)w; w += (size_t)E_NUM * T * sizeof(float);
    float* HB   = (float*)w; w += (size_t)T * TOPK * I_DIM * sizeof(float);
    float* HS   = (float*)w; w += (size_t)T * IS_DIM * sizeof(float);

    hipMemsetAsync(cnt, 0, E_NUM * sizeof(int), stream);
    router_k<<<T, 64, 0, stream>>>(X, RW, RB, CB, cnt, tok_id, tok_w, T);
    scan_k<<<1, 64, 0, stream>>>(cnt, offs);
    gateup_shared_k<<<dim3(T / TM, IS_DIM / TN), 256, 0, stream>>>(
        X, SWg, Sbg, SWu, Sbu, HS);
    down_shared_k<<<dim3(T / TM, H / TN), 256, 0, stream>>>(HS, SWd, Sbd, OUT);
    gateup_routed_k<<<dim3(T / TM, I_DIM / TN, E_NUM), 256, 0, stream>>>(
        X, GWg, Gbg, GWu, Gbu, cnt, offs, tok_id, HB, T);
    down_routed_k<<<dim3(T / TM, H / TN, E_NUM), 256, 0, stream>>>(
        HB, GWd, Gbd, cnt, offs, tok_id, tok_w, OUT, T);
}

// Round 3
// 585.367 us; speedup vs baseline: 1.4859x; 1.4859x over previous
//
#include <hip/hip_runtime.h>
#include <hip/hip_bf16.h>
#include <math.h>

// ---- problem constants ----
#define H 768
#define I_DIM 384
#define E_NUM 16
#define G_NUM 4
#define TOPK 4
#define IS_DIM 768
#define SCALE_F 2.5f
#define ECHUNK 4            // experts converted/processed per chunk

// ---- MFMA GEMM tiling ----
#define BM 128
#define BK 32
#define LDA 40   // padded LDS row stride in bf16 elems (80B: 2-way bank alias = free)

typedef __attribute__((ext_vector_type(8))) __bf16 bf16x8;
typedef __attribute__((ext_vector_type(4))) float f32x4;

static __device__ __forceinline__ unsigned short f2bf(float f) {
    __bf16 h = (__bf16)f;   // RNE convert
    return __builtin_bit_cast(unsigned short, h);
}

// =====================================================================
// Router: 1 wave per token.
// =====================================================================
__global__ __launch_bounds__(64) void router_k(
    const float* __restrict__ X, const float* __restrict__ RW,
    const float* __restrict__ RB, const float* __restrict__ CB,
    int* __restrict__ cnt, int* __restrict__ tok_id, float* __restrict__ tok_w,
    int T)
{
    const int t = blockIdx.x;
    const int lane = threadIdx.x;
    const int e = lane & 15;
    const int chunk = lane >> 4;
    const float* xr = X + (size_t)t * H + chunk * (H / 4);
    const float* wr = RW + (size_t)e * H + chunk * (H / 4);
    float s = 0.f;
#pragma unroll 4
    for (int j = 0; j < H / 4; j += 4) {
        float4 a = *(const float4*)(xr + j);
        float4 b = *(const float4*)(wr + j);
        s += a.x * b.x + a.y * b.y + a.z * b.z + a.w * b.w;
    }
    s += __shfl_xor(s, 16);
    s += __shfl_xor(s, 32);

    __shared__ float sc_s[E_NUM];
    __shared__ float sf_s[E_NUM];
    if (lane < E_NUM) {
        float logit = s + RB[e];
        float score = 1.f / (1.f + expf(-logit));
        sc_s[e] = score;
        sf_s[e] = score + CB[e];
    }
    __syncthreads();

    if (lane == 0) {
        float gs[G_NUM];
        for (int g = 0; g < G_NUM; ++g) {
            float m1 = -1e30f, m2 = -1e30f;
            for (int j = 0; j < E_NUM / G_NUM; ++j) {
                float v = sf_s[g * (E_NUM / G_NUM) + j];
                if (v > m1) { m2 = m1; m1 = v; }
                else if (v > m2) { m2 = v; }
            }
            gs[g] = m1 + m2;
        }
        int g1 = 0;
        for (int g = 1; g < G_NUM; ++g) if (gs[g] > gs[g1]) g1 = g;
        int g2 = -1;
        for (int g = 0; g < G_NUM; ++g) {
            if (g == g1) continue;
            if (g2 < 0 || gs[g] > gs[g2]) g2 = g;
        }
        float m[E_NUM];
        for (int i = 0; i < E_NUM; ++i) {
            int g = i >> 2;
            m[i] = (g == g1 || g == g2) ? sf_s[i] : 0.f;
        }
        float wsum = 0.f;
        int sel[TOPK]; float wv[TOPK];
        for (int k = 0; k < TOPK; ++k) {
            int best = 0; float bv = -1e30f;
            for (int i = 0; i < E_NUM; ++i)
                if (m[i] > bv) { bv = m[i]; best = i; }
            m[best] = -2e30f;
            sel[k] = best;
            wv[k] = sc_s[best];
            wsum += wv[k];
        }
        float inv = SCALE_F / (wsum + 1e-20f);
        for (int k = 0; k < TOPK; ++k) {
            int pos = atomicAdd(&cnt[sel[k]], 1);
            tok_id[sel[k] * T + pos] = t;
            tok_w[sel[k] * T + pos] = wv[k] * inv;
        }
    }
}

__global__ void scan_k(const int* __restrict__ cnt, int* __restrict__ offs)
{
    if (threadIdx.x == 0) {
        int a = 0;
        for (int e2 = 0; e2 < E_NUM; ++e2) { offs[e2] = a; a += cnt[e2]; }
        offs[E_NUM] = a;
    }
}

// =====================================================================
// fp32 [z][R][C] -> bf16 [z][C][R]  (transpose-convert via LDS)
// =====================================================================
__global__ __launch_bounds__(256) void tcvt_k(
    const float* __restrict__ src, unsigned short* __restrict__ dst, int R, int C)
{
    __shared__ unsigned short tile[32][33];
    const size_t mat = (size_t)blockIdx.z * R * C;
    const int r0 = blockIdx.y * 32, c0 = blockIdx.x * 32;
    const int t = threadIdx.x;
    const int lr = t >> 3, lc = (t & 7) * 4;
    float4 v = *(const float4*)(src + mat + (size_t)(r0 + lr) * C + c0 + lc);
    tile[lc + 0][lr] = f2bf(v.x);
    tile[lc + 1][lr] = f2bf(v.y);
    tile[lc + 2][lr] = f2bf(v.z);
    tile[lc + 3][lr] = f2bf(v.w);
    __syncthreads();
    ushort4 o;
    o.x = tile[lr][lc]; o.y = tile[lr][lc + 1];
    o.z = tile[lr][lc + 2]; o.w = tile[lr][lc + 3];
    *(ushort4*)(dst + mat + (size_t)(c0 + lr) * R + r0 + lc) = o;
}

// fp32 -> bf16 elementwise (X), 8 elems/thread
__global__ __launch_bounds__(256) void cvtx_k(
    const float* __restrict__ src, unsigned short* __restrict__ dst, int n8)
{
    int i = blockIdx.x * 256 + threadIdx.x;
    if (i >= n8) return;
    const float4* s = (const float4*)(src + (size_t)i * 8);
    float4 a = s[0], b = s[1];
    unsigned short u[8] = { f2bf(a.x), f2bf(a.y), f2bf(a.z), f2bf(a.w),
                            f2bf(b.x), f2bf(b.y), f2bf(b.z), f2bf(b.w) };
    *(uint4*)(dst + (size_t)i * 8) = *(uint4*)u;
}

// =====================================================================
// Fused gate+up MFMA GEMM: HO[r][n] = silu(A@Wg^T + bg) * (A@Wu^T + bu)
// 128x64 tile, 4 waves (2x2). Weights indexed chunk-locally (blockIdx.z);
// routing metadata indexed by global expert e = ebase + blockIdx.z.
// =====================================================================
template<bool GATHER>
__global__ __launch_bounds__(256) void gateup_mfma_k(
    const unsigned short* __restrict__ Xb,    // [T][H] bf16
    const unsigned short* __restrict__ WgT,   // [z][NI][H] bf16
    const unsigned short* __restrict__ WuT,
    const float* __restrict__ bgp,            // [(e)][NI]
    const float* __restrict__ bup,
    const int* __restrict__ cnt, const int* __restrict__ offs,
    const int* __restrict__ tok_id,
    unsigned short* __restrict__ HO,          // [(rows)][NI] bf16
    int T, int NI, int ebase)
{
    const int zz = blockIdx.z;
    const int e = GATHER ? (ebase + zz) : 0;
    const int ne = GATHER ? cnt[e] : T;
    const int m0 = blockIdx.x * BM;
    if (m0 >= ne) return;
    const int n0 = blockIdx.y * 64;

    const unsigned short* Wg = WgT + (size_t)zz * NI * H;
    const unsigned short* Wu = WuT + (size_t)zz * NI * H;
    const float* bg = bgp + (GATHER ? e * NI : 0);
    const float* bu = bup + (GATHER ? e * NI : 0);
    const int obase = GATHER ? offs[e] : 0;
    const int* tl = tok_id + (GATHER ? (size_t)e * T : 0);

    __shared__ unsigned short Al[BM * LDA];
    __shared__ unsigned short Bgl[64 * LDA];
    __shared__ unsigned short Bul[64 * LDA];

    const int tid = threadIdx.x;
    const int srow = tid >> 2;          // 0..63
    const int sseg = (tid & 3) * 8;     // k elem offset (16B)

    int r0i = m0 + srow, r1i = m0 + srow + 64;
    if (GATHER) { r0i = min(r0i, ne - 1); r1i = min(r1i, ne - 1); }
    const int tok0 = GATHER ? tl[r0i] : r0i;
    const int tok1 = GATHER ? tl[r1i] : r1i;
    const unsigned short* a0p = Xb + (size_t)tok0 * H + sseg;
    const unsigned short* a1p = Xb + (size_t)tok1 * H + sseg;
    const unsigned short* gsp = Wg + (size_t)(n0 + srow) * H + sseg;
    const unsigned short* usp = Wu + (size_t)(n0 + srow) * H + sseg;

    const int lane = tid & 63;
    const int wid = tid >> 6;
    const int wr = wid >> 1, wc = wid & 1;
    const int lrow = lane & 15;
    const int kseg = (lane >> 4) * 8;

    f32x4 accg[4][2] = {};
    f32x4 accu[4][2] = {};

    for (int k0 = 0; k0 < H; k0 += BK) {
        uint4 av0 = *(const uint4*)(a0p + k0);
        uint4 av1 = *(const uint4*)(a1p + k0);
        uint4 gv  = *(const uint4*)(gsp + k0);
        uint4 uv  = *(const uint4*)(usp + k0);
        __syncthreads();
        *(uint4*)&Al[srow * LDA + sseg] = av0;
        *(uint4*)&Al[(srow + 64) * LDA + sseg] = av1;
        *(uint4*)&Bgl[srow * LDA + sseg] = gv;
        *(uint4*)&Bul[srow * LDA + sseg] = uv;
        __syncthreads();
        bf16x8 af[4], gf[2], uf[2];
#pragma unroll
        for (int i = 0; i < 4; ++i)
            af[i] = *(const bf16x8*)&Al[(wr * 64 + i * 16 + lrow) * LDA + kseg];
#pragma unroll
        for (int j = 0; j < 2; ++j) {
            gf[j] = *(const bf16x8*)&Bgl[(wc * 32 + j * 16 + lrow) * LDA + kseg];
            uf[j] = *(const bf16x8*)&Bul[(wc * 32 + j * 16 + lrow) * LDA + kseg];
        }
#pragma unroll
        for (int i = 0; i < 4; ++i)
#pragma unroll
            for (int j = 0; j < 2; ++j) {
                accg[i][j] = __builtin_amdgcn_mfma_f32_16x16x32_bf16(af[i], gf[j], accg[i][j], 0, 0, 0);
                accu[i][j] = __builtin_amdgcn_mfma_f32_16x16x32_bf16(af[i], uf[j], accu[i][j], 0, 0, 0);
            }
    }

    const int q4 = (lane >> 4) * 4;   // C/D: col=lane&15, row=(lane>>4)*4+reg  [m89]
    const int cc = lane & 15;
#pragma unroll
    for (int i = 0; i < 4; ++i)
#pragma unroll
        for (int j = 0; j < 2; ++j)
#pragma unroll
            for (int r = 0; r < 4; ++r) {
                const int row = m0 + wr * 64 + i * 16 + q4 + r;
                if (!GATHER || row < ne) {
                    const int col = n0 + wc * 32 + j * 16 + cc;
                    float g = accg[i][j][r] + bg[col];
                    float u = accu[i][j][r] + bu[col];
                    float s = g / (1.f + expf(-g)) * u;
                    HO[(size_t)(obase + row) * NI + col] = f2bf(s);
                }
            }
}

// =====================================================================
// Down-proj MFMA GEMM: 128x128 tile, 4 waves (2x2).
// SCATTER: OUT[tok] += w*(acc+bd) (atomics); else direct write + bias.
// =====================================================================
template<bool SCATTER>
__global__ __launch_bounds__(256) void down_mfma_k(
    const unsigned short* __restrict__ Hb,    // [(rows)][K] bf16
    const unsigned short* __restrict__ WdT,   // [z][H][K] bf16
    const float* __restrict__ bdp,            // [(e)][H]
    const int* __restrict__ cnt, const int* __restrict__ offs,
    const int* __restrict__ tok_id, const float* __restrict__ tok_w,
    float* __restrict__ OUT, int T, int K, int ebase)
{
    const int zz = blockIdx.z;
    const int e = SCATTER ? (ebase + zz) : 0;
    const int ne = SCATTER ? cnt[e] : T;
    const int m0 = blockIdx.x * BM;
    if (m0 >= ne) return;
    const int n0 = blockIdx.y * 128;

    const unsigned short* Wd = WdT + (size_t)zz * H * K;
    const float* bd = bdp + (SCATTER ? e * H : 0);
    const int abase = SCATTER ? offs[e] : 0;

    __shared__ unsigned short Al[BM * LDA];
    __shared__ unsigned short Bl[128 * LDA];

    const int tid = threadIdx.x;
    const int srow = tid >> 2;
    const int sseg = (tid & 3) * 8;

    const int r0i = min(m0 + srow, ne - 1);
    const int r1i = min(m0 + srow + 64, ne - 1);
    const unsigned short* a0p = Hb + (size_t)(abase + r0i) * K + sseg;
    const unsigned short* a1p = Hb + (size_t)(abase + r1i) * K + sseg;
    const unsigned short* b0p = Wd + (size_t)(n0 + srow) * K + sseg;
    const unsigned short* b1p = Wd + (size_t)(n0 + srow + 64) * K + sseg;

    const int lane = tid & 63;
    const int wid = tid >> 6;
    const int wr = wid >> 1, wc = wid & 1;
    const int lrow = lane & 15;
    const int kseg = (lane >> 4) * 8;

    f32x4 acc[4][4] = {};

    for (int k0 = 0; k0 < K; k0 += BK) {
        uint4 av0 = *(const uint4*)(a0p + k0);
        uint4 av1 = *(const uint4*)(a1p + k0);
        uint4 bv0 = *(const uint4*)(b0p + k0);
        uint4 bv1 = *(const uint4*)(b1p + k0);
        __syncthreads();
        *(uint4*)&Al[srow * LDA + sseg] = av0;
        *(uint4*)&Al[(srow + 64) * LDA + sseg] = av1;
        *(uint4*)&Bl[srow * LDA + sseg] = bv0;
        *(uint4*)&Bl[(srow + 64) * LDA + sseg] = bv1;
        __syncthreads();
        bf16x8 af[4], bfr[4];
#pragma unroll
        for (int i = 0; i < 4; ++i) {
            af[i]  = *(const bf16x8*)&Al[(wr * 64 + i * 16 + lrow) * LDA + kseg];
            bfr[i] = *(const bf16x8*)&Bl[(wc * 64 + i * 16 + lrow) * LDA + kseg];
        }
#pragma unroll
        for (int i = 0; i < 4; ++i)
#pragma unroll
            for (int j = 0; j < 4; ++j)
                acc[i][j] = __builtin_amdgcn_mfma_f32_16x16x32_bf16(af[i], bfr[j], acc[i][j], 0, 0, 0);
    }

    const int q4 = (lane >> 4) * 4;
    const int cc = lane & 15;
#pragma unroll
    for (int i = 0; i < 4; ++i) {
        const int rbase = m0 + wr * 64 + i * 16 + q4;
        if (SCATTER) {
#pragma unroll
            for (int r = 0; r < 4; ++r) {
                const int row = rbase + r;
                if (row < ne) {
                    const int tok = tok_id[(size_t)e * T + row];
                    const float w = tok_w[(size_t)e * T + row];
#pragma unroll
                    for (int j = 0; j < 4; ++j) {
                        const int col = n0 + wc * 64 + j * 16 + cc;
                        atomicAdd(&OUT[(size_t)tok * H + col], w * (acc[i][j][r] + bd[col]));
                    }
                }
            }
        } else {
#pragma unroll
            for (int r = 0; r < 4; ++r) {
                const int row = rbase + r;
#pragma unroll
                for (int j = 0; j < 4; ++j) {
                    const int col = n0 + wc * 64 + j * 16 + cc;
                    OUT[(size_t)row * H + col] = acc[i][j][r] + bd[col];
                }
            }
        }
    }
}

extern "C" void kernel_launch(void* const* d_in, const int* in_sizes, int n_in,
                              void* d_out, int out_size, void* d_ws, size_t ws_size,
                              hipStream_t stream)
{
    const float* X   = (const float*)d_in[0];
    const float* RW  = (const float*)d_in[1];
    const float* RB  = (const float*)d_in[2];
    const float* CB  = (const float*)d_in[3];
    const float* GWg = (const float*)d_in[4];
    const float* Gbg = (const float*)d_in[5];
    const float* GWu = (const float*)d_in[6];
    const float* Gbu = (const float*)d_in[7];
    const float* GWd = (const float*)d_in[8];
    const float* Gbd = (const float*)d_in[9];
    const float* SWg = (const float*)d_in[10];
    const float* Sbg = (const float*)d_in[11];
    const float* SWu = (const float*)d_in[12];
    const float* Sbu = (const float*)d_in[13];
    const float* SWd = (const float*)d_in[14];
    const float* Sbd = (const float*)d_in[15];
    float* OUT = (float*)d_out;
    const int T = in_sizes[0] / H;   // 2048

    // ---- workspace carve-up (~13.75 MB total; round-1 proved 19.1 MB safe) ----
    char* w = (char*)d_ws;
    int* cnt     = (int*)w;            w += 256;
    int* offs    = (int*)w;            w += 256;
    int* tok_id  = (int*)w;            w += (size_t)E_NUM * T * sizeof(int);     // 128 KB
    float* tok_w = (float*)w;          w += (size_t)E_NUM * T * sizeof(float);   // 128 KB
    unsigned short* Xb = (unsigned short*)w; w += (size_t)T * H * 2;             // 3.0 MB
    // union: HSs (shared hidden, T*IS*2 = 3.0 MB) dead before HBr (routed
    // hidden, T*TOPK*I*2 = 6.0 MB) is written -> share one region.
    unsigned short* HSs = (unsigned short*)w;
    unsigned short* HBr = (unsigned short*)w; w += (size_t)T * TOPK * I_DIM * 2; // 6.0 MB
    // weight region, reused: shared {WgT,WuT} -> shared WdT -> per-chunk
    // routed {WgT,WuT} -> routed WdT. 4.5 MB.
    unsigned short* WB = (unsigned short*)w;  w += (size_t)ECHUNK * 2 * I_DIM * H * 2;

    hipMemsetAsync(cnt, 0, E_NUM * sizeof(int), stream);

    // routing + activation convert
    router_k<<<T, 64, 0, stream>>>(X, RW, RB, CB, cnt, tok_id, tok_w, T);
    scan_k<<<1, 64, 0, stream>>>(cnt, offs);
    cvtx_k<<<(T * H / 8 + 255) / 256, 256, 0, stream>>>(X, Xb, T * H / 8);

    // ---- shared expert ----
    unsigned short* SWgT = WB;
    unsigned short* SWuT = WB + (size_t)IS_DIM * H;
    tcvt_k<<<dim3(IS_DIM / 32, H / 32, 1), 256, 0, stream>>>(SWg, SWgT, H, IS_DIM);
    tcvt_k<<<dim3(IS_DIM / 32, H / 32, 1), 256, 0, stream>>>(SWu, SWuT, H, IS_DIM);
    gateup_mfma_k<false><<<dim3(T / BM, IS_DIM / 64, 1), 256, 0, stream>>>(
        Xb, SWgT, SWuT, Sbg, Sbu, nullptr, nullptr, nullptr, HSs, T, IS_DIM, 0);
    unsigned short* SWdT = WB;   // aliases SWgT (dead after gateup)
    tcvt_k<<<dim3(H / 32, IS_DIM / 32, 1), 256, 0, stream>>>(SWd, SWdT, IS_DIM, H);
    down_mfma_k<false><<<dim3(T / BM, H / 128, 1), 256, 0, stream>>>(
        HSs, SWdT, Sbd, nullptr, nullptr, nullptr, nullptr, OUT, T, IS_DIM, 0);

    // ---- routed experts, 4 chunks of 4 (weight region reused per chunk) ----
    for (int c = 0; c < E_NUM / ECHUNK; ++c) {
        const int eb = c * ECHUNK;
        unsigned short* WgT = WB;
        unsigned short* WuT = WB + (size_t)ECHUNK * I_DIM * H;
        tcvt_k<<<dim3(I_DIM / 32, H / 32, ECHUNK), 256, 0, stream>>>(
            GWg + (size_t)eb * H * I_DIM, WgT, H, I_DIM);
        tcvt_k<<<dim3(I_DIM / 32, H / 32, ECHUNK), 256, 0, stream>>>(
            GWu + (size_t)eb * H * I_DIM, WuT, H, I_DIM);
        gateup_mfma_k<true><<<dim3(T / BM, I_DIM / 64, ECHUNK), 256, 0, stream>>>(
            Xb, WgT, WuT, Gbg, Gbu, cnt, offs, tok_id, HBr, T, I_DIM, eb);
        unsigned short* WdT = WB;   // aliases WgT (dead after gateup)
        tcvt_k<<<dim3(H / 32, I_DIM / 32, ECHUNK), 256, 0, stream>>>(
            GWd + (size_t)eb * I_DIM * H, WdT, I_DIM, H);
        down_mfma_k<true><<<dim3(T / BM, H / 128, ECHUNK), 256, 0, stream>>>(
            HBr, WdT, Gbd, cnt, offs, tok_id, tok_w, OUT, T, I_DIM, eb);
    }
}

// Round 8
// 362.460 us; speedup vs baseline: 2.3997x; 1.6150x over previous
//
#include <hip/hip_runtime.h>
#include <hip/hip_bf16.h>
#include <math.h>

// ---- problem constants ----
#define H 768
#define I_DIM 384
#define E_NUM 16
#define G_NUM 4
#define TOPK 4
#define IS_DIM 768
#define SCALE_F 2.5f

// ---- MFMA GEMM tiling ----
#define BM 128
#define BK 32
#define LDA 40   // bf16 LDS row stride (80 B, 16B-aligned rows for b128 reads)

typedef __attribute__((ext_vector_type(8))) __bf16 bf16x8;
typedef __attribute__((ext_vector_type(4))) float f32x4;

static __device__ __forceinline__ unsigned short f2bf(float f) {
    __bf16 h = (__bf16)f;   // RNE convert
    return __builtin_bit_cast(unsigned short, h);
}

// granule-swizzled LDS offset: element (row, k granule c=k>>3) at
// row*LDA + ((c ^ (row>>3))&3)*8. Spreads transpose-writes and b128 reads
// across banks (2-way worst case ~ free per m136).
static __device__ __forceinline__ int swz8(int row, int c) {
    return row * LDA + (((c ^ (row >> 3)) & 3) << 3);
}

// =====================================================================
// Router pass 1: scores + per-token top-4. 4 waves/block, 1 token/wave.
// No atomics.
// =====================================================================
__global__ __launch_bounds__(256) void router_score_k(
    const float* __restrict__ X, const float* __restrict__ RW,
    const float* __restrict__ RB, const float* __restrict__ CB,
    int* __restrict__ sel_out, float* __restrict__ w_out, int T)
{
    const int wid = threadIdx.x >> 6;
    const int lane = threadIdx.x & 63;
    const int t = blockIdx.x * 4 + wid;
    const int e = lane & 15;
    const int chunk = lane >> 4;
    const float* xr = X + (size_t)t * H + chunk * (H / 4);
    const float* wr = RW + (size_t)e * H + chunk * (H / 4);
    float s = 0.f;
#pragma unroll 4
    for (int j = 0; j < H / 4; j += 4) {
        float4 a = *(const float4*)(xr + j);
        float4 b = *(const float4*)(wr + j);
        s += a.x * b.x + a.y * b.y + a.z * b.z + a.w * b.w;
    }
    s += __shfl_xor(s, 16);
    s += __shfl_xor(s, 32);

    __shared__ float sc_s[4][E_NUM];
    __shared__ float sf_s[4][E_NUM];
    if (lane < E_NUM) {
        float logit = s + RB[e];
        float score = 1.f / (1.f + expf(-logit));
        sc_s[wid][e] = score;
        sf_s[wid][e] = score + CB[e];
    }
    __syncthreads();

    if (lane == 0) {
        float gs[G_NUM];
        for (int g = 0; g < G_NUM; ++g) {
            float m1 = -1e30f, m2 = -1e30f;
            for (int j = 0; j < E_NUM / G_NUM; ++j) {
                float v = sf_s[wid][g * (E_NUM / G_NUM) + j];
                if (v > m1) { m2 = m1; m1 = v; }
                else if (v > m2) { m2 = v; }
            }
            gs[g] = m1 + m2;
        }
        int g1 = 0;
        for (int g = 1; g < G_NUM; ++g) if (gs[g] > gs[g1]) g1 = g;
        int g2 = -1;
        for (int g = 0; g < G_NUM; ++g) {
            if (g == g1) continue;
            if (g2 < 0 || gs[g] > gs[g2]) g2 = g;
        }
        float m[E_NUM];
        for (int i = 0; i < E_NUM; ++i) {
            int g = i >> 2;
            m[i] = (g == g1 || g == g2) ? sf_s[wid][i] : 0.f;
        }
        float wsum = 0.f;
        int sel[TOPK]; float wv[TOPK];
        for (int k = 0; k < TOPK; ++k) {
            int best = 0; float bv = -1e30f;
            for (int i = 0; i < E_NUM; ++i)
                if (m[i] > bv) { bv = m[i]; best = i; }
            m[best] = -2e30f;
            sel[k] = best;
            wv[k] = sc_s[wid][best];
            wsum += wv[k];
        }
        float inv = SCALE_F / (wsum + 1e-20f);
        int4 so = { sel[0], sel[1], sel[2], sel[3] };
        float4 wo = { wv[0] * inv, wv[1] * inv, wv[2] * inv, wv[3] * inv };
        *(int4*)&sel_out[(size_t)t * 4] = so;
        *(float4*)&w_out[(size_t)t * 4] = wo;
    }
}

// =====================================================================
// Router pass 2: per-expert compact token lists, deterministic
// (ascending token order) via ballot + prefix scan. 1 block per expert.
// =====================================================================
__global__ __launch_bounds__(256) void build_lists_k(
    const int* __restrict__ sel, const float* __restrict__ wv,
    int* __restrict__ cnt, int* __restrict__ tok_id, float* __restrict__ tok_w,
    int T)
{
    const int e = blockIdx.x;
    const int tid = threadIdx.x;
    const int wid = tid >> 6, lane = tid & 63;
    __shared__ int wtot[4];
    __shared__ int base_s;
    if (tid == 0) base_s = 0;
    __syncthreads();

    for (int t0 = 0; t0 < T; t0 += 256) {
        const int t = t0 + tid;
        int flag = 0; float myw = 0.f;
        int4 sv = *(const int4*)&sel[(size_t)t * 4];
        float4 wq = *(const float4*)&wv[(size_t)t * 4];
        if (sv.x == e) { flag = 1; myw = wq.x; }
        if (sv.y == e) { flag = 1; myw = wq.y; }
        if (sv.z == e) { flag = 1; myw = wq.z; }
        if (sv.w == e) { flag = 1; myw = wq.w; }
        unsigned long long mb = __ballot(flag);
        if (lane == 0) wtot[wid] = __popcll(mb);
        __syncthreads();
        int wo = 0;
#pragma unroll
        for (int q = 0; q < 4; ++q) if (q < wid) wo += wtot[q];
        const int stot = wtot[0] + wtot[1] + wtot[2] + wtot[3];
        const int mypos = base_s + wo + __popcll(mb & ((1ull << lane) - 1ull));
        if (flag) {
            tok_id[(size_t)e * T + mypos] = t;
            tok_w[(size_t)e * T + mypos] = myw;
        }
        __syncthreads();
        if (tid == 0) base_s += stot;
    }
    __syncthreads();
    if (tid == 0) cnt[e] = base_s;
}

// exclusive scan over E=16 expert counts -> compact h-buffer offsets
__global__ void scan_k(const int* __restrict__ cnt, int* __restrict__ offs)
{
    if (threadIdx.x == 0) {
        int a = 0;
        for (int e2 = 0; e2 < E_NUM; ++e2) { offs[e2] = a; a += cnt[e2]; }
        offs[E_NUM] = a;
    }
}

// fp32 -> bf16 elementwise (X), 8 elems/thread
__global__ __launch_bounds__(256) void cvtx_k(
    const float* __restrict__ src, unsigned short* __restrict__ dst, int n8)
{
    int i = blockIdx.x * 256 + threadIdx.x;
    if (i >= n8) return;
    const float4* s = (const float4*)(src + (size_t)i * 8);
    float4 a = s[0], b = s[1];
    unsigned short u[8] = { f2bf(a.x), f2bf(a.y), f2bf(a.z), f2bf(a.w),
                            f2bf(b.x), f2bf(b.y), f2bf(b.z), f2bf(b.w) };
    *(uint4*)(dst + (size_t)i * 8) = *(uint4*)u;
}

// write 4 bf16 into transposed+swizzled LDS B tile: cols n..n+3, row k=kr
static __device__ __forceinline__ void wr4(
    unsigned short* Bt, int n, int kr, float4 v)
{
    const int cg = kr >> 3, kl = kr & 7;
    Bt[(n + 0) * LDA + (((cg ^ ((n + 0) >> 3)) & 3) << 3) + kl] = f2bf(v.x);
    Bt[(n + 1) * LDA + (((cg ^ ((n + 1) >> 3)) & 3) << 3) + kl] = f2bf(v.y);
    Bt[(n + 2) * LDA + (((cg ^ ((n + 2) >> 3)) & 3) << 3) + kl] = f2bf(v.z);
    Bt[(n + 3) * LDA + (((cg ^ ((n + 3) >> 3)) & 3) << 3) + kl] = f2bf(v.w);
}

// =====================================================================
// Fused gate+up MFMA GEMM. A: bf16 [.][H] (gathered rows when GATHER).
// B: fp32 [K=H][NI] read directly, converted+transposed into LDS.
// 128x64 tile, 4 waves (2x2), per-wave 64x32 of each of gate/up.
// =====================================================================
template<bool GATHER>
__global__ __launch_bounds__(256) void gateup_mfma_k(
    const unsigned short* __restrict__ Xb,    // [T][H] bf16
    const float* __restrict__ WgP,            // [(e)][H][NI] fp32
    const float* __restrict__ WuP,
    const float* __restrict__ bgp, const float* __restrict__ bup,
    const int* __restrict__ cnt, const int* __restrict__ offs,
    const int* __restrict__ tok_id,
    unsigned short* __restrict__ HO,          // [(rows)][NI] bf16
    int T, int NI)
{
    const int e = GATHER ? blockIdx.z : 0;
    const int ne = GATHER ? cnt[e] : T;
    const int m0 = blockIdx.x * BM;
    if (m0 >= ne) return;
    const int n0 = blockIdx.y * 64;

    const float* Wg = WgP + (GATHER ? (size_t)e * H * NI : 0);
    const float* Wu = WuP + (GATHER ? (size_t)e * H * NI : 0);
    const float* bg = bgp + (GATHER ? e * NI : 0);
    const float* bu = bup + (GATHER ? e * NI : 0);
    const int obase = GATHER ? offs[e] : 0;
    const int* tl = tok_id + (GATHER ? (size_t)e * T : 0);

    __shared__ unsigned short Al[BM * LDA];
    __shared__ unsigned short Bgl[64 * LDA];
    __shared__ unsigned short Bul[64 * LDA];

    const int tid = threadIdx.x;
    // A staging map: 2 rows x 16B each
    const int srow = tid >> 2;
    const int sseg = (tid & 3) * 8;
    // B staging map: rows kr0,kr0+16; cols c4..c4+3 (coalesced float4)
    const int kr0 = tid >> 4;          // 0..15
    const int c4 = (tid & 15) * 4;     // 0..60

    int r0i = m0 + srow, r1i = m0 + srow + 64;
    if (GATHER) { r0i = min(r0i, ne - 1); r1i = min(r1i, ne - 1); }
    const int tok0 = GATHER ? tl[r0i] : r0i;
    const int tok1 = GATHER ? tl[r1i] : r1i;
    const unsigned short* a0p = Xb + (size_t)tok0 * H + sseg;
    const unsigned short* a1p = Xb + (size_t)tok1 * H + sseg;

    const int lane = tid & 63;
    const int wid = tid >> 6;
    const int wr = wid >> 1, wc = wid & 1;
    const int lrow = lane & 15;
    const int lkc = lane >> 4;         // k-granule 0..3 over BK=32

    f32x4 accg[4][2] = {};
    f32x4 accu[4][2] = {};

    for (int k0 = 0; k0 < H; k0 += BK) {
        uint4 av0 = *(const uint4*)(a0p + k0);
        uint4 av1 = *(const uint4*)(a1p + k0);
        float4 gv0 = *(const float4*)(Wg + (size_t)(k0 + kr0) * NI + n0 + c4);
        float4 gv1 = *(const float4*)(Wg + (size_t)(k0 + kr0 + 16) * NI + n0 + c4);
        float4 uv0 = *(const float4*)(Wu + (size_t)(k0 + kr0) * NI + n0 + c4);
        float4 uv1 = *(const float4*)(Wu + (size_t)(k0 + kr0 + 16) * NI + n0 + c4);
        __syncthreads();
        *(uint4*)&Al[swz8(srow, tid & 3)] = av0;
        *(uint4*)&Al[swz8(srow + 64, tid & 3)] = av1;
        wr4(Bgl, c4, kr0, gv0);
        wr4(Bgl, c4, kr0 + 16, gv1);
        wr4(Bul, c4, kr0, uv0);
        wr4(Bul, c4, kr0 + 16, uv1);
        __syncthreads();
        bf16x8 af[4], gf[2], uf[2];
#pragma unroll
        for (int i = 0; i < 4; ++i)
            af[i] = *(const bf16x8*)&Al[swz8(wr * 64 + i * 16 + lrow, lkc)];
#pragma unroll
        for (int j = 0; j < 2; ++j) {
            gf[j] = *(const bf16x8*)&Bgl[swz8(wc * 32 + j * 16 + lrow, lkc)];
            uf[j] = *(const bf16x8*)&Bul[swz8(wc * 32 + j * 16 + lrow, lkc)];
        }
#pragma unroll
        for (int i = 0; i < 4; ++i)
#pragma unroll
            for (int j = 0; j < 2; ++j) {
                accg[i][j] = __builtin_amdgcn_mfma_f32_16x16x32_bf16(af[i], gf[j], accg[i][j], 0, 0, 0);
                accu[i][j] = __builtin_amdgcn_mfma_f32_16x16x32_bf16(af[i], uf[j], accu[i][j], 0, 0, 0);
            }
    }

    const int q4 = (lane >> 4) * 4;   // C/D: col=lane&15, row=(lane>>4)*4+reg  [m89]
    const int cc = lane & 15;
#pragma unroll
    for (int i = 0; i < 4; ++i)
#pragma unroll
        for (int j = 0; j < 2; ++j)
#pragma unroll
            for (int r = 0; r < 4; ++r) {
                const int row = m0 + wr * 64 + i * 16 + q4 + r;
                if (!GATHER || row < ne) {
                    const int col = n0 + wc * 32 + j * 16 + cc;
                    float g = accg[i][j][r] + bg[col];
                    float u = accu[i][j][r] + bu[col];
                    float s = g / (1.f + expf(-g)) * u;
                    HO[(size_t)(obase + row) * NI + col] = f2bf(s);
                }
            }
}

// =====================================================================
// Down-proj MFMA GEMM: 128x128 tile, 4 waves (2x2), per-wave 64x64.
// B: fp32 [K][H] read directly, converted+transposed into LDS.
// SCATTER: OUT[tok] += w*(acc+bd) (atomics); else direct write + bias.
// =====================================================================
template<bool SCATTER>
__global__ __launch_bounds__(256) void down_mfma_k(
    const unsigned short* __restrict__ Hb,    // [(rows)][K] bf16
    const float* __restrict__ WdP,            // [(e)][K][H] fp32
    const float* __restrict__ bdp,
    const int* __restrict__ cnt, const int* __restrict__ offs,
    const int* __restrict__ tok_id, const float* __restrict__ tok_w,
    float* __restrict__ OUT, int T, int K)
{
    const int e = SCATTER ? blockIdx.z : 0;
    const int ne = SCATTER ? cnt[e] : T;
    const int m0 = blockIdx.x * BM;
    if (m0 >= ne) return;
    const int n0 = blockIdx.y * 128;

    const float* Wd = WdP + (SCATTER ? (size_t)e * K * H : 0);
    const float* bd = bdp + (SCATTER ? e * H : 0);
    const int abase = SCATTER ? offs[e] : 0;

    __shared__ unsigned short Al[BM * LDA];
    __shared__ unsigned short Bl[128 * LDA];

    const int tid = threadIdx.x;
    const int srow = tid >> 2;
    const int sseg = (tid & 3) * 8;
    const int kr0 = tid >> 5;          // 0..7 (rows +0,+8,+16,+24)
    const int c4 = (tid & 31) * 4;     // 0..124

    const int r0i = min(m0 + srow, ne - 1);
    const int r1i = min(m0 + srow + 64, ne - 1);
    const unsigned short* a0p = Hb + (size_t)(abase + r0i) * K + sseg;
    const unsigned short* a1p = Hb + (size_t)(abase + r1i) * K + sseg;

    const int lane = tid & 63;
    const int wid = tid >> 6;
    const int wr = wid >> 1, wc = wid & 1;
    const int lrow = lane & 15;
    const int lkc = lane >> 4;

    f32x4 acc[4][4] = {};

    for (int k0 = 0; k0 < K; k0 += BK) {
        uint4 av0 = *(const uint4*)(a0p + k0);
        uint4 av1 = *(const uint4*)(a1p + k0);
        float4 bv0 = *(const float4*)(Wd + (size_t)(k0 + kr0) * H + n0 + c4);
        float4 bv1 = *(const float4*)(Wd + (size_t)(k0 + kr0 + 8) * H + n0 + c4);
        float4 bv2 = *(const float4*)(Wd + (size_t)(k0 + kr0 + 16) * H + n0 + c4);
        float4 bv3 = *(const float4*)(Wd + (size_t)(k0 + kr0 + 24) * H + n0 + c4);
        __syncthreads();
        *(uint4*)&Al[swz8(srow, tid & 3)] = av0;
        *(uint4*)&Al[swz8(srow + 64, tid & 3)] = av1;
        wr4(Bl, c4, kr0, bv0);
        wr4(Bl, c4, kr0 + 8, bv1);
        wr4(Bl, c4, kr0 + 16, bv2);
        wr4(Bl, c4, kr0 + 24, bv3);
        __syncthreads();
        bf16x8 af[4], bfr[4];
#pragma unroll
        for (int i = 0; i < 4; ++i) {
            af[i]  = *(const bf16x8*)&Al[swz8(wr * 64 + i * 16 + lrow, lkc)];
            bfr[i] = *(const bf16x8*)&Bl[swz8(wc * 64 + i * 16 + lrow, lkc)];
        }
#pragma unroll
        for (int i = 0; i < 4; ++i)
#pragma unroll
            for (int j = 0; j < 4; ++j)
                acc[i][j] = __builtin_amdgcn_mfma_f32_16x16x32_bf16(af[i], bfr[j], acc[i][j], 0, 0, 0);
    }

    const int q4 = (lane >> 4) * 4;
    const int cc = lane & 15;
#pragma unroll
    for (int i = 0; i < 4; ++i) {
        const int rbase = m0 + wr * 64 + i * 16 + q4;
        if (SCATTER) {
#pragma unroll
            for (int r = 0; r < 4; ++r) {
                const int row = rbase + r;
                if (row < ne) {
                    const int tok = tok_id[(size_t)e * T + row];
                    const float w = tok_w[(size_t)e * T + row];
#pragma unroll
                    for (int j = 0; j < 4; ++j) {
                        const int col = n0 + wc * 64 + j * 16 + cc;
                        atomicAdd(&OUT[(size_t)tok * H + col], w * (acc[i][j][r] + bd[col]));
                    }
                }
            }
        } else {
#pragma unroll
            for (int r = 0; r < 4; ++r) {
                const int row = rbase + r;
#pragma unroll
                for (int j = 0; j < 4; ++j) {
                    const int col = n0 + wc * 64 + j * 16 + cc;
                    OUT[(size_t)row * H + col] = acc[i][j][r] + bd[col];
                }
            }
        }
    }
}

extern "C" void kernel_launch(void* const* d_in, const int* in_sizes, int n_in,
                              void* d_out, int out_size, void* d_ws, size_t ws_size,
                              hipStream_t stream)
{
    const float* X   = (const float*)d_in[0];
    const float* RW  = (const float*)d_in[1];
    const float* RB  = (const float*)d_in[2];
    const float* CB  = (const float*)d_in[3];
    const float* GWg = (const float*)d_in[4];
    const float* Gbg = (const float*)d_in[5];
    const float* GWu = (const float*)d_in[6];
    const float* Gbu = (const float*)d_in[7];
    const float* GWd = (const float*)d_in[8];
    const float* Gbd = (const float*)d_in[9];
    const float* SWg = (const float*)d_in[10];
    const float* Sbg = (const float*)d_in[11];
    const float* SWu = (const float*)d_in[12];
    const float* Sbu = (const float*)d_in[13];
    const float* SWd = (const float*)d_in[14];
    const float* Sbd = (const float*)d_in[15];
    float* OUT = (float*)d_out;
    const int T = in_sizes[0] / H;   // 2048

    // ---- workspace (~9.4 MB; 19.1 MB proven safe) ----
    char* w = (char*)d_ws;
    int* cnt     = (int*)w;            w += 256;
    int* offs    = (int*)w;            w += 256;
    int* sel     = (int*)w;            w += (size_t)T * TOPK * sizeof(int);      // 32 KB
    float* selw  = (float*)w;          w += (size_t)T * TOPK * sizeof(float);    // 32 KB
    int* tok_id  = (int*)w;            w += (size_t)E_NUM * T * sizeof(int);     // 128 KB
    float* tok_w = (float*)w;          w += (size_t)E_NUM * T * sizeof(float);   // 128 KB
    unsigned short* Xb = (unsigned short*)w; w += (size_t)T * H * 2;             // 3.0 MB
    // HSs (shared hidden, 3 MB) dead before HBr (routed hidden, 6 MB): union.
    unsigned short* HSs = (unsigned short*)w;
    unsigned short* HBr = (unsigned short*)w; w += (size_t)T * TOPK * I_DIM * 2; // 6.0 MB

    // routing (atomic-free, deterministic)
    router_score_k<<<T / 4, 256, 0, stream>>>(X, RW, RB, CB, sel, selw, T);
    build_lists_k<<<E_NUM, 256, 0, stream>>>(sel, selw, cnt, tok_id, tok_w, T);
    scan_k<<<1, 64, 0, stream>>>(cnt, offs);
    cvtx_k<<<(T * H / 8 + 255) / 256, 256, 0, stream>>>(X, Xb, T * H / 8);

    // shared expert (weights fp32 [K][N], converted in-GEMM)
    gateup_mfma_k<false><<<dim3(T / BM, IS_DIM / 64, 1), 256, 0, stream>>>(
        Xb, SWg, SWu, Sbg, Sbu, nullptr, nullptr, nullptr, HSs, T, IS_DIM);
    down_mfma_k<false><<<dim3(T / BM, H / 128, 1), 256, 0, stream>>>(
        HSs, SWd, Sbd, nullptr, nullptr, nullptr, nullptr, OUT, T, IS_DIM);

    // routed experts, all 16 in one launch each
    gateup_mfma_k<true><<<dim3(T / BM, I_DIM / 64, E_NUM), 256, 0, stream>>>(
        Xb, GWg, GWu, Gbg, Gbu, cnt, offs, tok_id, HBr, T, I_DIM);
    down_mfma_k<true><<<dim3(T / BM, H / 128, E_NUM), 256, 0, stream>>>(
        HBr, GWd, Gbd, cnt, offs, tok_id, tok_w, OUT, T, I_DIM);
}

// Round 12
// 347.368 us; speedup vs baseline: 2.5039x; 1.0434x over previous
//
#include <hip/hip_runtime.h>
#include <hip/hip_bf16.h>
#include <math.h>

// ---- problem constants ----
#define H 768
#define I_DIM 384
#define E_NUM 16
#define G_NUM 4
#define TOPK 4
#define IS_DIM 768
#define SCALE_F 2.5f

// ---- MFMA GEMM tiling ----
#define BM 128
#define BK 32
#define LDA 40   // bf16 LDS row stride (80 B, 16B-aligned rows for b128 ops)

typedef __attribute__((ext_vector_type(8))) __bf16 bf16x8;
typedef __attribute__((ext_vector_type(4))) float f32x4;

static __device__ __forceinline__ unsigned short f2bf(float f) {
    __bf16 h = (__bf16)f;   // RNE convert
    return __builtin_bit_cast(unsigned short, h);
}

// granule-swizzled LDS offset: element (row, k granule c=k>>3) at
// row*LDA + ((c ^ (row>>3))&3)*8. Write and read use the same involution.
static __device__ __forceinline__ int swz8(int row, int c) {
    return row * LDA + (((c ^ (row >> 3)) & 3) << 3);
}

// =====================================================================
// Router pass 1: scores + per-token top-4 + fused X->bf16 conversion.
// 4 waves/block, 1 token/wave. No atomics.
// =====================================================================
__global__ __launch_bounds__(256) void router_score_k(
    const float* __restrict__ X, const float* __restrict__ RW,
    const float* __restrict__ RB, const float* __restrict__ CB,
    int* __restrict__ sel_out, float* __restrict__ w_out,
    unsigned short* __restrict__ Xb, int T)
{
    const int wid = threadIdx.x >> 6;
    const int lane = threadIdx.x & 63;
    const int t = blockIdx.x * 4 + wid;
    const int e = lane & 15;
    const int chunk = lane >> 4;
    const float* xr = X + (size_t)t * H + chunk * (H / 4);
    const float* wr = RW + (size_t)e * H + chunk * (H / 4);
    float s = 0.f;
#pragma unroll 4
    for (int j = 0; j < H / 4; j += 4) {
        float4 a = *(const float4*)(xr + j);
        float4 b = *(const float4*)(wr + j);
        s += a.x * b.x + a.y * b.y + a.z * b.z + a.w * b.w;
    }
    s += __shfl_xor(s, 16);
    s += __shfl_xor(s, 32);

    // fused X -> bf16 (wave converts its token's row; X row is cache-hot)
    {
        const float* xrow = X + (size_t)t * H;
        unsigned short* brow = Xb + (size_t)t * H;
#pragma unroll
        for (int p = 0; p < 3; ++p) {
            float4 v = *(const float4*)(xrow + p * 256 + lane * 4);
            ushort4 o = { f2bf(v.x), f2bf(v.y), f2bf(v.z), f2bf(v.w) };
            *(ushort4*)(brow + p * 256 + lane * 4) = o;
        }
    }

    __shared__ float sc_s[4][E_NUM];
    __shared__ float sf_s[4][E_NUM];
    if (lane < E_NUM) {
        float logit = s + RB[e];
        float score = 1.f / (1.f + expf(-logit));
        sc_s[wid][e] = score;
        sf_s[wid][e] = score + CB[e];
    }
    __syncthreads();

    if (lane == 0) {
        float gs[G_NUM];
        for (int g = 0; g < G_NUM; ++g) {
            float m1 = -1e30f, m2 = -1e30f;
            for (int j = 0; j < E_NUM / G_NUM; ++j) {
                float v = sf_s[wid][g * (E_NUM / G_NUM) + j];
                if (v > m1) { m2 = m1; m1 = v; }
                else if (v > m2) { m2 = v; }
            }
            gs[g] = m1 + m2;
        }
        int g1 = 0;
        for (int g = 1; g < G_NUM; ++g) if (gs[g] > gs[g1]) g1 = g;
        int g2 = -1;
        for (int g = 0; g < G_NUM; ++g) {
            if (g == g1) continue;
            if (g2 < 0 || gs[g] > gs[g2]) g2 = g;
        }
        float m[E_NUM];
        for (int i = 0; i < E_NUM; ++i) {
            int g = i >> 2;
            m[i] = (g == g1 || g == g2) ? sf_s[wid][i] : 0.f;
        }
        float wsum = 0.f;
        int sel[TOPK]; float wv[TOPK];
        for (int k = 0; k < TOPK; ++k) {
            int best = 0; float bv = -1e30f;
            for (int i = 0; i < E_NUM; ++i)
                if (m[i] > bv) { bv = m[i]; best = i; }
            m[best] = -2e30f;
            sel[k] = best;
            wv[k] = sc_s[wid][best];
            wsum += wv[k];
        }
        float inv = SCALE_F / (wsum + 1e-20f);
        int4 so = { sel[0], sel[1], sel[2], sel[3] };
        float4 wo = { wv[0] * inv, wv[1] * inv, wv[2] * inv, wv[3] * inv };
        *(int4*)&sel_out[(size_t)t * 4] = so;
        *(float4*)&w_out[(size_t)t * 4] = wo;
    }
}

// =====================================================================
// Router pass 2: per-expert compact token lists (deterministic).
// =====================================================================
__global__ __launch_bounds__(256) void build_lists_k(
    const int* __restrict__ sel, const float* __restrict__ wv,
    int* __restrict__ cnt, int* __restrict__ tok_id, float* __restrict__ tok_w,
    int T)
{
    const int e = blockIdx.x;
    const int tid = threadIdx.x;
    const int wid = tid >> 6, lane = tid & 63;
    __shared__ int wtot[4];
    __shared__ int base_s;
    if (tid == 0) base_s = 0;
    __syncthreads();

    for (int t0 = 0; t0 < T; t0 += 256) {
        const int t = t0 + tid;
        int flag = 0; float myw = 0.f;
        int4 sv = *(const int4*)&sel[(size_t)t * 4];
        float4 wq = *(const float4*)&wv[(size_t)t * 4];
        if (sv.x == e) { flag = 1; myw = wq.x; }
        if (sv.y == e) { flag = 1; myw = wq.y; }
        if (sv.z == e) { flag = 1; myw = wq.z; }
        if (sv.w == e) { flag = 1; myw = wq.w; }
        unsigned long long mb = __ballot(flag);
        if (lane == 0) wtot[wid] = __popcll(mb);
        __syncthreads();
        int wo = 0;
#pragma unroll
        for (int q = 0; q < 4; ++q) if (q < wid) wo += wtot[q];
        const int stot = wtot[0] + wtot[1] + wtot[2] + wtot[3];
        const int mypos = base_s + wo + __popcll(mb & ((1ull << lane) - 1ull));
        if (flag) {
            tok_id[(size_t)e * T + mypos] = t;
            tok_w[(size_t)e * T + mypos] = myw;
        }
        __syncthreads();
        if (tid == 0) base_s += stot;
    }
    __syncthreads();
    if (tid == 0) cnt[e] = base_s;
}

__global__ void scan_k(const int* __restrict__ cnt, int* __restrict__ offs)
{
    if (threadIdx.x == 0) {
        int a = 0;
        for (int e2 = 0; e2 < E_NUM; ++e2) { offs[e2] = a; a += cnt[e2]; }
        offs[E_NUM] = a;
    }
}

// write 4 bf16 into transposed+swizzled LDS B tile: cols n..n+3, row k=kr
static __device__ __forceinline__ void wr4(
    unsigned short* Bt, int n, int kr, float4 v)
{
    const int cg = kr >> 3, kl = kr & 7;
    Bt[(n + 0) * LDA + (((cg ^ ((n + 0) >> 3)) & 3) << 3) + kl] = f2bf(v.x);
    Bt[(n + 1) * LDA + (((cg ^ ((n + 1) >> 3)) & 3) << 3) + kl] = f2bf(v.y);
    Bt[(n + 2) * LDA + (((cg ^ ((n + 2) >> 3)) & 3) << 3) + kl] = f2bf(v.z);
    Bt[(n + 3) * LDA + (((cg ^ ((n + 3) >> 3)) & 3) << 3) + kl] = f2bf(v.w);
}

// =====================================================================
// Merged gate+up MFMA GEMM (shared expert = z==E_NUM, routed = z<E_NUM).
// 2-phase register pipeline: next-tile global loads issue BEFORE the MFMA
// cluster, so the vmcnt drain at the next barrier lands after compute.
// =====================================================================
__global__ __launch_bounds__(256) void gateup_all_k(
    const unsigned short* __restrict__ Xb,    // [T][H] bf16
    const float* __restrict__ GWg, const float* __restrict__ GWu,
    const float* __restrict__ Gbg, const float* __restrict__ Gbu,
    const float* __restrict__ SWg, const float* __restrict__ SWu,
    const float* __restrict__ Sbg, const float* __restrict__ Sbu,
    const int* __restrict__ cnt, const int* __restrict__ offs,
    const int* __restrict__ tok_id,
    unsigned short* __restrict__ HBr,         // [T*TOPK][I_DIM] bf16
    unsigned short* __restrict__ HSs,         // [T][IS_DIM] bf16
    int T)
{
    const int z = blockIdx.z;
    const bool SH = (z == E_NUM);
    const int NI = SH ? IS_DIM : I_DIM;
    const int n0 = blockIdx.y * 64;
    if (n0 >= NI) return;
    const int ne = SH ? T : cnt[z];
    const int m0 = blockIdx.x * BM;
    if (m0 >= ne) return;

    const float* Wg = SH ? SWg : GWg + (size_t)z * H * I_DIM;
    const float* Wu = SH ? SWu : GWu + (size_t)z * H * I_DIM;
    const float* bg = SH ? Sbg : Gbg + z * I_DIM;
    const float* bu = SH ? Sbu : Gbu + z * I_DIM;
    unsigned short* HO = SH ? HSs : HBr;
    const int obase = SH ? 0 : offs[z];
    const int* tl = tok_id + (size_t)z * T;    // deref'd only when !SH

    __shared__ unsigned short Al[BM * LDA];
    __shared__ unsigned short Bgl[64 * LDA];
    __shared__ unsigned short Bul[64 * LDA];

    const int tid = threadIdx.x;
    const int srow = tid >> 2;
    const int sseg = (tid & 3) * 8;
    const int kr0 = tid >> 4;          // 0..15
    const int c4 = (tid & 15) * 4;     // 0..60

    int r0i = m0 + srow, r1i = m0 + srow + 64;
    if (!SH) { r0i = min(r0i, ne - 1); r1i = min(r1i, ne - 1); }
    const int tok0 = SH ? r0i : tl[r0i];
    const int tok1 = SH ? r1i : tl[r1i];
    const unsigned short* a0p = Xb + (size_t)tok0 * H + sseg;
    const unsigned short* a1p = Xb + (size_t)tok1 * H + sseg;

    const int lane = tid & 63;
    const int wvid = tid >> 6;
    const int wr = wvid >> 1, wc = wvid & 1;
    const int lrow = lane & 15;
    const int lkc = lane >> 4;

    f32x4 accg[4][2] = {};
    f32x4 accu[4][2] = {};

    uint4 av0, av1; float4 gv0, gv1, uv0, uv1;
#define GU_LOADS(K)                                                        \
    av0 = *(const uint4*)(a0p + (K));                                      \
    av1 = *(const uint4*)(a1p + (K));                                      \
    gv0 = *(const float4*)(Wg + (size_t)((K) + kr0) * NI + n0 + c4);       \
    gv1 = *(const float4*)(Wg + (size_t)((K) + kr0 + 16) * NI + n0 + c4);  \
    uv0 = *(const float4*)(Wu + (size_t)((K) + kr0) * NI + n0 + c4);       \
    uv1 = *(const float4*)(Wu + (size_t)((K) + kr0 + 16) * NI + n0 + c4);

    GU_LOADS(0);
    for (int k0 = 0; k0 < H; k0 += BK) {
        __syncthreads();
        *(uint4*)&Al[swz8(srow, tid & 3)] = av0;
        *(uint4*)&Al[swz8(srow + 64, tid & 3)] = av1;
        wr4(Bgl, c4, kr0, gv0);
        wr4(Bgl, c4, kr0 + 16, gv1);
        wr4(Bul, c4, kr0, uv0);
        wr4(Bul, c4, kr0 + 16, uv1);
        __syncthreads();
        if (k0 + BK < H) { GU_LOADS(k0 + BK); }   // prefetch overlaps MFMA
        bf16x8 af[4], gf[2], uf[2];
#pragma unroll
        for (int i = 0; i < 4; ++i)
            af[i] = *(const bf16x8*)&Al[swz8(wr * 64 + i * 16 + lrow, lkc)];
#pragma unroll
        for (int j = 0; j < 2; ++j) {
            gf[j] = *(const bf16x8*)&Bgl[swz8(wc * 32 + j * 16 + lrow, lkc)];
            uf[j] = *(const bf16x8*)&Bul[swz8(wc * 32 + j * 16 + lrow, lkc)];
        }
#pragma unroll
        for (int i = 0; i < 4; ++i)
#pragma unroll
            for (int j = 0; j < 2; ++j) {
                accg[i][j] = __builtin_amdgcn_mfma_f32_16x16x32_bf16(af[i], gf[j], accg[i][j], 0, 0, 0);
                accu[i][j] = __builtin_amdgcn_mfma_f32_16x16x32_bf16(af[i], uf[j], accu[i][j], 0, 0, 0);
            }
    }
#undef GU_LOADS

    const int q4 = (lane >> 4) * 4;   // C/D: col=lane&15, row=(lane>>4)*4+reg  [m89]
    const int cc = lane & 15;
#pragma unroll
    for (int i = 0; i < 4; ++i)
#pragma unroll
        for (int j = 0; j < 2; ++j)
#pragma unroll
            for (int r = 0; r < 4; ++r) {
                const int row = m0 + wr * 64 + i * 16 + q4 + r;
                if (SH || row < ne) {
                    const int col = n0 + wc * 32 + j * 16 + cc;
                    float g = accg[i][j][r] + bg[col];
                    float u = accu[i][j][r] + bu[col];
                    float s = g / (1.f + expf(-g)) * u;
                    HO[(size_t)(obase + row) * NI + col] = f2bf(s);
                }
            }
}

// =====================================================================
// Down-proj MFMA GEMM (2-phase pipelined): 128x128 tile, 4 waves.
// SCATTER: OUT[tok] += w*(acc+bd) (atomics); else direct write + bias.
// =====================================================================
template<bool SCATTER>
__global__ __launch_bounds__(256) void down_mfma_k(
    const unsigned short* __restrict__ Hb,    // [(rows)][K] bf16
    const float* __restrict__ WdP,            // [(e)][K][H] fp32
    const float* __restrict__ bdp,
    const int* __restrict__ cnt, const int* __restrict__ offs,
    const int* __restrict__ tok_id, const float* __restrict__ tok_w,
    float* __restrict__ OUT, int T, int K)
{
    const int e = SCATTER ? blockIdx.z : 0;
    const int ne = SCATTER ? cnt[e] : T;
    const int m0 = blockIdx.x * BM;
    if (m0 >= ne) return;
    const int n0 = blockIdx.y * 128;

    const float* Wd = WdP + (SCATTER ? (size_t)e * K * H : 0);
    const float* bd = bdp + (SCATTER ? e * H : 0);
    const int abase = SCATTER ? offs[e] : 0;

    __shared__ unsigned short Al[BM * LDA];
    __shared__ unsigned short Bl[128 * LDA];

    const int tid = threadIdx.x;
    const int srow = tid >> 2;
    const int sseg = (tid & 3) * 8;
    const int kr0 = tid >> 5;          // 0..7 (rows +0,+8,+16,+24)
    const int c4 = (tid & 31) * 4;     // 0..124

    const int r0i = min(m0 + srow, ne - 1);
    const int r1i = min(m0 + srow + 64, ne - 1);
    const unsigned short* a0p = Hb + (size_t)(abase + r0i) * K + sseg;
    const unsigned short* a1p = Hb + (size_t)(abase + r1i) * K + sseg;

    const int lane = tid & 63;
    const int wvid = tid >> 6;
    const int wr = wvid >> 1, wc = wvid & 1;
    const int lrow = lane & 15;
    const int lkc = lane >> 4;

    f32x4 acc[4][4] = {};

    uint4 av0, av1; float4 bv0, bv1, bv2, bv3;
#define DN_LOADS(K0)                                                        \
    av0 = *(const uint4*)(a0p + (K0));                                      \
    av1 = *(const uint4*)(a1p + (K0));                                      \
    bv0 = *(const float4*)(Wd + (size_t)((K0) + kr0) * H + n0 + c4);        \
    bv1 = *(const float4*)(Wd + (size_t)((K0) + kr0 + 8) * H + n0 + c4);    \
    bv2 = *(const float4*)(Wd + (size_t)((K0) + kr0 + 16) * H + n0 + c4);   \
    bv3 = *(const float4*)(Wd + (size_t)((K0) + kr0 + 24) * H + n0 + c4);

    DN_LOADS(0);
    for (int k0 = 0; k0 < K; k0 += BK) {
        __syncthreads();
        *(uint4*)&Al[swz8(srow, tid & 3)] = av0;
        *(uint4*)&Al[swz8(srow + 64, tid & 3)] = av1;
        wr4(Bl, c4, kr0, bv0);
        wr4(Bl, c4, kr0 + 8, bv1);
        wr4(Bl, c4, kr0 + 16, bv2);
        wr4(Bl, c4, kr0 + 24, bv3);
        __syncthreads();
        if (k0 + BK < K) { DN_LOADS(k0 + BK); }   // prefetch overlaps MFMA
        bf16x8 af[4], bfr[4];
#pragma unroll
        for (int i = 0; i < 4; ++i) {
            af[i]  = *(const bf16x8*)&Al[swz8(wr * 64 + i * 16 + lrow, lkc)];
            bfr[i] = *(const bf16x8*)&Bl[swz8(wc * 64 + i * 16 + lrow, lkc)];
        }
#pragma unroll
        for (int i = 0; i < 4; ++i)
#pragma unroll
            for (int j = 0; j < 4; ++j)
                acc[i][j] = __builtin_amdgcn_mfma_f32_16x16x32_bf16(af[i], bfr[j], acc[i][j], 0, 0, 0);
    }
#undef DN_LOADS

    const int q4 = (lane >> 4) * 4;
    const int cc = lane & 15;
#pragma unroll
    for (int i = 0; i < 4; ++i) {
        const int rbase = m0 + wr * 64 + i * 16 + q4;
        if (SCATTER) {
#pragma unroll
            for (int r = 0; r < 4; ++r) {
                const int row = rbase + r;
                if (row < ne) {
                    const int tok = tok_id[(size_t)e * T + row];
                    const float w = tok_w[(size_t)e * T + row];
#pragma unroll
                    for (int j = 0; j < 4; ++j) {
                        const int col = n0 + wc * 64 + j * 16 + cc;
                        atomicAdd(&OUT[(size_t)tok * H + col], w * (acc[i][j][r] + bd[col]));
                    }
                }
            }
        } else {
#pragma unroll
            for (int r = 0; r < 4; ++r) {
                const int row = rbase + r;
#pragma unroll
                for (int j = 0; j < 4; ++j) {
                    const int col = n0 + wc * 64 + j * 16 + cc;
                    OUT[(size_t)row * H + col] = acc[i][j][r] + bd[col];
                }
            }
        }
    }
}

extern "C" void kernel_launch(void* const* d_in, const int* in_sizes, int n_in,
                              void* d_out, int out_size, void* d_ws, size_t ws_size,
                              hipStream_t stream)
{
    const float* X   = (const float*)d_in[0];
    const float* RW  = (const float*)d_in[1];
    const float* RB  = (const float*)d_in[2];
    const float* CB  = (const float*)d_in[3];
    const float* GWg = (const float*)d_in[4];
    const float* Gbg = (const float*)d_in[5];
    const float* GWu = (const float*)d_in[6];
    const float* Gbu = (const float*)d_in[7];
    const float* GWd = (const float*)d_in[8];
    const float* Gbd = (const float*)d_in[9];
    const float* SWg = (const float*)d_in[10];
    const float* Sbg = (const float*)d_in[11];
    const float* SWu = (const float*)d_in[12];
    const float* Sbu = (const float*)d_in[13];
    const float* SWd = (const float*)d_in[14];
    const float* Sbd = (const float*)d_in[15];
    float* OUT = (float*)d_out;
    const int T = in_sizes[0] / H;   // 2048

    // ---- workspace (~12.4 MB; 19.1 MB proven safe). HSs and HBr are
    // DISJOINT (merged gate-up writes both concurrently). ----
    char* w = (char*)d_ws;
    int* cnt     = (int*)w;            w += 256;
    int* offs    = (int*)w;            w += 256;
    int* sel     = (int*)w;            w += (size_t)T * TOPK * sizeof(int);
    float* selw  = (float*)w;          w += (size_t)T * TOPK * sizeof(float);
    int* tok_id  = (int*)w;            w += (size_t)E_NUM * T * sizeof(int);
    float* tok_w = (float*)w;          w += (size_t)E_NUM * T * sizeof(float);
    unsigned short* Xb  = (unsigned short*)w; w += (size_t)T * H * 2;              // 3.0 MB
    unsigned short* HSs = (unsigned short*)w; w += (size_t)T * IS_DIM * 2;         // 3.0 MB
    unsigned short* HBr = (unsigned short*)w; w += (size_t)T * TOPK * I_DIM * 2;   // 6.0 MB

    // routing + fused activation convert
    router_score_k<<<T / 4, 256, 0, stream>>>(X, RW, RB, CB, sel, selw, Xb, T);
    build_lists_k<<<E_NUM, 256, 0, stream>>>(sel, selw, cnt, tok_id, tok_w, T);
    scan_k<<<1, 64, 0, stream>>>(cnt, offs);

    // merged gate+up: z=0..15 routed experts, z=16 shared expert
    gateup_all_k<<<dim3(T / BM, IS_DIM / 64, E_NUM + 1), 256, 0, stream>>>(
        Xb, GWg, GWu, Gbg, Gbu, SWg, SWu, Sbg, Sbu,
        cnt, offs, tok_id, HBr, HSs, T);

    // shared expert down (initializes OUT)
    down_mfma_k<false><<<dim3(T / BM, H / 128, 1), 256, 0, stream>>>(
        HSs, SWd, Sbd, nullptr, nullptr, nullptr, nullptr, OUT, T, IS_DIM);

    // routed experts down (scatter-add)
    down_mfma_k<true><<<dim3(T / BM, H / 128, E_NUM), 256, 0, stream>>>(
        HBr, GWd, Gbd, cnt, offs, tok_id, tok_w, OUT, T, I_DIM);
}

// Round 14
// 292.443 us; speedup vs baseline: 2.9742x; 1.1878x over previous
//
#include <hip/hip_runtime.h>
#include <hip/hip_bf16.h>
#include <math.h>

// ---- problem constants ----
#define H 768
#define I_DIM 384
#define E_NUM 16
#define G_NUM 4
#define TOPK 4
#define IS_DIM 768
#define SCALE_F 2.5f

// ---- MFMA GEMM tiling ----
#define BM 128
#define BK 32
#define LDA 40   // bf16 LDS row stride (80 B, 16B-aligned rows for b128 ops)

typedef __attribute__((ext_vector_type(8))) __bf16 bf16x8;
typedef __attribute__((ext_vector_type(4))) float f32x4;

static __device__ __forceinline__ unsigned short f2bf(float f) {
    __bf16 h = (__bf16)f;   // RNE convert
    return __builtin_bit_cast(unsigned short, h);
}

// granule-swizzled LDS offset (write & read use the same involution)
static __device__ __forceinline__ int swz8(int row, int c) {
    return row * LDA + (((c ^ (row >> 3)) & 3) << 3);
}

// =====================================================================
// Router pass 1: scores + per-token top-4 + fused X->bf16 conversion.
// =====================================================================
__global__ __launch_bounds__(256) void router_score_k(
    const float* __restrict__ X, const float* __restrict__ RW,
    const float* __restrict__ RB, const float* __restrict__ CB,
    int* __restrict__ sel_out, float* __restrict__ w_out,
    unsigned short* __restrict__ Xb, int T)
{
    const int wid = threadIdx.x >> 6;
    const int lane = threadIdx.x & 63;
    const int t = blockIdx.x * 4 + wid;
    const int e = lane & 15;
    const int chunk = lane >> 4;
    const float* xr = X + (size_t)t * H + chunk * (H / 4);
    const float* wr = RW + (size_t)e * H + chunk * (H / 4);
    float s = 0.f;
#pragma unroll 4
    for (int j = 0; j < H / 4; j += 4) {
        float4 a = *(const float4*)(xr + j);
        float4 b = *(const float4*)(wr + j);
        s += a.x * b.x + a.y * b.y + a.z * b.z + a.w * b.w;
    }
    s += __shfl_xor(s, 16);
    s += __shfl_xor(s, 32);

    {   // fused X -> bf16
        const float* xrow = X + (size_t)t * H;
        unsigned short* brow = Xb + (size_t)t * H;
#pragma unroll
        for (int p = 0; p < 3; ++p) {
            float4 v = *(const float4*)(xrow + p * 256 + lane * 4);
            ushort4 o = { f2bf(v.x), f2bf(v.y), f2bf(v.z), f2bf(v.w) };
            *(ushort4*)(brow + p * 256 + lane * 4) = o;
        }
    }

    __shared__ float sc_s[4][E_NUM];
    __shared__ float sf_s[4][E_NUM];
    if (lane < E_NUM) {
        float logit = s + RB[e];
        float score = 1.f / (1.f + expf(-logit));
        sc_s[wid][e] = score;
        sf_s[wid][e] = score + CB[e];
    }
    __syncthreads();

    if (lane == 0) {
        float gs[G_NUM];
        for (int g = 0; g < G_NUM; ++g) {
            float m1 = -1e30f, m2 = -1e30f;
            for (int j = 0; j < E_NUM / G_NUM; ++j) {
                float v = sf_s[wid][g * (E_NUM / G_NUM) + j];
                if (v > m1) { m2 = m1; m1 = v; }
                else if (v > m2) { m2 = v; }
            }
            gs[g] = m1 + m2;
        }
        int g1 = 0;
        for (int g = 1; g < G_NUM; ++g) if (gs[g] > gs[g1]) g1 = g;
        int g2 = -1;
        for (int g = 0; g < G_NUM; ++g) {
            if (g == g1) continue;
            if (g2 < 0 || gs[g] > gs[g2]) g2 = g;
        }
        float m[E_NUM];
        for (int i = 0; i < E_NUM; ++i) {
            int g = i >> 2;
            m[i] = (g == g1 || g == g2) ? sf_s[wid][i] : 0.f;
        }
        float wsum = 0.f;
        int sel[TOPK]; float wv[TOPK];
        for (int k = 0; k < TOPK; ++k) {
            int best = 0; float bv = -1e30f;
            for (int i = 0; i < E_NUM; ++i)
                if (m[i] > bv) { bv = m[i]; best = i; }
            m[best] = -2e30f;
            sel[k] = best;
            wv[k] = sc_s[wid][best];
            wsum += wv[k];
        }
        float inv = SCALE_F / (wsum + 1e-20f);
        int4 so = { sel[0], sel[1], sel[2], sel[3] };
        float4 wo = { wv[0] * inv, wv[1] * inv, wv[2] * inv, wv[3] * inv };
        *(int4*)&sel_out[(size_t)t * 4] = so;
        *(float4*)&w_out[(size_t)t * 4] = wo;
    }
}

// =====================================================================
// Router pass 2: per-expert compact token lists (deterministic).
// =====================================================================
__global__ __launch_bounds__(256) void build_lists_k(
    const int* __restrict__ sel, const float* __restrict__ wv,
    int* __restrict__ cnt, int* __restrict__ tok_id, float* __restrict__ tok_w,
    int T)
{
    const int e = blockIdx.x;
    const int tid = threadIdx.x;
    const int wid = tid >> 6, lane = tid & 63;
    __shared__ int wtot[4];
    __shared__ int base_s;
    if (tid == 0) base_s = 0;
    __syncthreads();

    for (int t0 = 0; t0 < T; t0 += 256) {
        const int t = t0 + tid;
        int flag = 0; float myw = 0.f;
        int4 sv = *(const int4*)&sel[(size_t)t * 4];
        float4 wq = *(const float4*)&wv[(size_t)t * 4];
        if (sv.x == e) { flag = 1; myw = wq.x; }
        if (sv.y == e) { flag = 1; myw = wq.y; }
        if (sv.z == e) { flag = 1; myw = wq.z; }
        if (sv.w == e) { flag = 1; myw = wq.w; }
        unsigned long long mb = __ballot(flag);
        if (lane == 0) wtot[wid] = __popcll(mb);
        __syncthreads();
        int wo = 0;
#pragma unroll
        for (int q = 0; q < 4; ++q) if (q < wid) wo += wtot[q];
        const int stot = wtot[0] + wtot[1] + wtot[2] + wtot[3];
        const int mypos = base_s + wo + __popcll(mb & ((1ull << lane) - 1ull));
        if (flag) {
            tok_id[(size_t)e * T + mypos] = t;
            tok_w[(size_t)e * T + mypos] = myw;
        }
        __syncthreads();
        if (tid == 0) base_s += stot;
    }
    __syncthreads();
    if (tid == 0) cnt[e] = base_s;
}

__global__ void scan_k(const int* __restrict__ cnt, int* __restrict__ offs)
{
    if (threadIdx.x == 0) {
        int a = 0;
        for (int e2 = 0; e2 < E_NUM; ++e2) { offs[e2] = a; a += cnt[e2]; }
        offs[E_NUM] = a;
    }
}

// write 4 bf16 into transposed+swizzled LDS B tile: cols n..n+3, row k=kr
static __device__ __forceinline__ void wr4(
    unsigned short* Bt, int n, int kr, float4 v)
{
    const int cg = kr >> 3, kl = kr & 7;
    Bt[(n + 0) * LDA + (((cg ^ ((n + 0) >> 3)) & 3) << 3) + kl] = f2bf(v.x);
    Bt[(n + 1) * LDA + (((cg ^ ((n + 1) >> 3)) & 3) << 3) + kl] = f2bf(v.y);
    Bt[(n + 2) * LDA + (((cg ^ ((n + 2) >> 3)) & 3) << 3) + kl] = f2bf(v.z);
    Bt[(n + 3) * LDA + (((cg ^ ((n + 3) >> 3)) & 3) << 3) + kl] = f2bf(v.w);
}

// XCD-group swizzle decode: physical p -> (x, g) with p%8 == g%8, so all
// m-blocks x of weight-group g land on the SAME XCD (round-robin dispatch).
// GX must be 16 (x = (p>>3)&15).
static __device__ __forceinline__ bool decode_swz(
    int p, int GTOT, int& x, int& g)
{
    const int xcd = p & 7;
    const int rem = p >> 3;
    x = rem & 15;
    g = xcd + 8 * (rem >> 4);
    return g < GTOT;
}

// =====================================================================
// Merged gate+up MFMA GEMM (z==E_NUM: shared; z<E_NUM: routed).
// 2-phase register pipeline + XCD-group-swizzled 1D grid.
// groups g = y + 12*z (y: 64-col slice, z: expert), GTOT = 12*17 = 204.
// =====================================================================
__global__ __launch_bounds__(256) void gateup_all_k(
    const unsigned short* __restrict__ Xb,    // [T][H] bf16
    const float* __restrict__ GWg, const float* __restrict__ GWu,
    const float* __restrict__ Gbg, const float* __restrict__ Gbu,
    const float* __restrict__ SWg, const float* __restrict__ SWu,
    const float* __restrict__ Sbg, const float* __restrict__ Sbu,
    const int* __restrict__ cnt, const int* __restrict__ offs,
    const int* __restrict__ tok_id,
    unsigned short* __restrict__ HBr,         // [T*TOPK][I_DIM] bf16
    unsigned short* __restrict__ HSs,         // [T][IS_DIM] bf16
    int T)
{
    int x, g;
    if (!decode_swz(blockIdx.x, 12 * (E_NUM + 1), x, g)) return;
    const int y = g % 12, z = g / 12;
    const bool SH = (z == E_NUM);
    const int NI = SH ? IS_DIM : I_DIM;
    const int n0 = y * 64;
    if (n0 >= NI) return;
    const int ne = SH ? T : cnt[z];
    const int m0 = x * BM;
    if (m0 >= ne) return;

    const float* Wg = SH ? SWg : GWg + (size_t)z * H * I_DIM;
    const float* Wu = SH ? SWu : GWu + (size_t)z * H * I_DIM;
    const float* bg = SH ? Sbg : Gbg + z * I_DIM;
    const float* bu = SH ? Sbu : Gbu + z * I_DIM;
    unsigned short* HO = SH ? HSs : HBr;
    const int obase = SH ? 0 : offs[z];
    const int* tl = tok_id + (size_t)z * T;    // deref'd only when !SH

    __shared__ unsigned short Al[BM * LDA];
    __shared__ unsigned short Bgl[64 * LDA];
    __shared__ unsigned short Bul[64 * LDA];

    const int tid = threadIdx.x;
    const int srow = tid >> 2;
    const int sseg = (tid & 3) * 8;
    const int kr0 = tid >> 4;          // 0..15
    const int c4 = (tid & 15) * 4;     // 0..60

    int r0i = m0 + srow, r1i = m0 + srow + 64;
    if (!SH) { r0i = min(r0i, ne - 1); r1i = min(r1i, ne - 1); }
    const int tok0 = SH ? r0i : tl[r0i];
    const int tok1 = SH ? r1i : tl[r1i];
    const unsigned short* a0p = Xb + (size_t)tok0 * H + sseg;
    const unsigned short* a1p = Xb + (size_t)tok1 * H + sseg;

    const int lane = tid & 63;
    const int wvid = tid >> 6;
    const int wr = wvid >> 1, wc = wvid & 1;
    const int lrow = lane & 15;
    const int lkc = lane >> 4;

    f32x4 accg[4][2] = {};
    f32x4 accu[4][2] = {};

    uint4 av0, av1; float4 gv0, gv1, uv0, uv1;
#define GU_LOADS(K)                                                        \
    av0 = *(const uint4*)(a0p + (K));                                      \
    av1 = *(const uint4*)(a1p + (K));                                      \
    gv0 = *(const float4*)(Wg + (size_t)((K) + kr0) * NI + n0 + c4);       \
    gv1 = *(const float4*)(Wg + (size_t)((K) + kr0 + 16) * NI + n0 + c4);  \
    uv0 = *(const float4*)(Wu + (size_t)((K) + kr0) * NI + n0 + c4);       \
    uv1 = *(const float4*)(Wu + (size_t)((K) + kr0 + 16) * NI + n0 + c4);

    GU_LOADS(0);
    for (int k0 = 0; k0 < H; k0 += BK) {
        __syncthreads();
        *(uint4*)&Al[swz8(srow, tid & 3)] = av0;
        *(uint4*)&Al[swz8(srow + 64, tid & 3)] = av1;
        wr4(Bgl, c4, kr0, gv0);
        wr4(Bgl, c4, kr0 + 16, gv1);
        wr4(Bul, c4, kr0, uv0);
        wr4(Bul, c4, kr0 + 16, uv1);
        __syncthreads();
        if (k0 + BK < H) { GU_LOADS(k0 + BK); }   // prefetch overlaps MFMA
        bf16x8 af[4], gf[2], uf[2];
#pragma unroll
        for (int i = 0; i < 4; ++i)
            af[i] = *(const bf16x8*)&Al[swz8(wr * 64 + i * 16 + lrow, lkc)];
#pragma unroll
        for (int j = 0; j < 2; ++j) {
            gf[j] = *(const bf16x8*)&Bgl[swz8(wc * 32 + j * 16 + lrow, lkc)];
            uf[j] = *(const bf16x8*)&Bul[swz8(wc * 32 + j * 16 + lrow, lkc)];
        }
#pragma unroll
        for (int i = 0; i < 4; ++i)
#pragma unroll
            for (int j = 0; j < 2; ++j) {
                accg[i][j] = __builtin_amdgcn_mfma_f32_16x16x32_bf16(af[i], gf[j], accg[i][j], 0, 0, 0);
                accu[i][j] = __builtin_amdgcn_mfma_f32_16x16x32_bf16(af[i], uf[j], accu[i][j], 0, 0, 0);
            }
    }
#undef GU_LOADS

    const int q4 = (lane >> 4) * 4;   // C/D: col=lane&15, row=(lane>>4)*4+reg  [m89]
    const int cc = lane & 15;
#pragma unroll
    for (int i = 0; i < 4; ++i)
#pragma unroll
        for (int j = 0; j < 2; ++j)
#pragma unroll
            for (int r = 0; r < 4; ++r) {
                const int row = m0 + wr * 64 + i * 16 + q4 + r;
                if (SH || row < ne) {
                    const int col = n0 + wc * 32 + j * 16 + cc;
                    float gq = accg[i][j][r] + bg[col];
                    float u = accu[i][j][r] + bu[col];
                    float s = gq / (1.f + expf(-gq)) * u;
                    HO[(size_t)(obase + row) * NI + col] = f2bf(s);
                }
            }
}

// =====================================================================
// Merged down-proj (z==E_NUM: shared; z<E_NUM: routed), all-atomic into
// zero-init'd OUT. 2-phase pipeline + XCD-group-swizzled 1D grid.
// groups g = y + 6*z (y: 128-col slice), GTOT = 6*17 = 102.
// =====================================================================
__global__ __launch_bounds__(256) void down_all_k(
    const unsigned short* __restrict__ HBr,   // [T*TOPK][I_DIM] bf16
    const unsigned short* __restrict__ HSs,   // [T][IS_DIM] bf16
    const float* __restrict__ GWd, const float* __restrict__ Gbd,
    const float* __restrict__ SWd, const float* __restrict__ Sbd,
    const int* __restrict__ cnt, const int* __restrict__ offs,
    const int* __restrict__ tok_id, const float* __restrict__ tok_w,
    float* __restrict__ OUT, int T)
{
    int x, g;
    if (!decode_swz(blockIdx.x, 6 * (E_NUM + 1), x, g)) return;
    const int y = g % 6, z = g / 6;
    const bool SH = (z == E_NUM);
    const int ne = SH ? T : cnt[z];
    const int m0 = x * BM;
    if (m0 >= ne) return;
    const int n0 = y * 128;
    const int K = SH ? IS_DIM : I_DIM;

    const float* Wd = SH ? SWd : GWd + (size_t)z * I_DIM * H;
    const float* bd = SH ? Sbd : Gbd + (size_t)z * H;
    const unsigned short* Hb = SH ? HSs : HBr;
    const int abase = SH ? 0 : offs[z];

    __shared__ unsigned short Al[BM * LDA];
    __shared__ unsigned short Bl[128 * LDA];

    const int tid = threadIdx.x;
    const int srow = tid >> 2;
    const int sseg = (tid & 3) * 8;
    const int kr0 = tid >> 5;          // 0..7 (rows +0,+8,+16,+24)
    const int c4 = (tid & 31) * 4;     // 0..124

    const int r0i = min(m0 + srow, ne - 1);
    const int r1i = min(m0 + srow + 64, ne - 1);
    const unsigned short* a0p = Hb + (size_t)(abase + r0i) * K + sseg;
    const unsigned short* a1p = Hb + (size_t)(abase + r1i) * K + sseg;

    const int lane = tid & 63;
    const int wvid = tid >> 6;
    const int wr = wvid >> 1, wc = wvid & 1;
    const int lrow = lane & 15;
    const int lkc = lane >> 4;

    f32x4 acc[4][4] = {};

    uint4 av0, av1; float4 bv0, bv1, bv2, bv3;
#define DN_LOADS(K0)                                                        \
    av0 = *(const uint4*)(a0p + (K0));                                      \
    av1 = *(const uint4*)(a1p + (K0));                                      \
    bv0 = *(const float4*)(Wd + (size_t)((K0) + kr0) * H + n0 + c4);        \
    bv1 = *(const float4*)(Wd + (size_t)((K0) + kr0 + 8) * H + n0 + c4);    \
    bv2 = *(const float4*)(Wd + (size_t)((K0) + kr0 + 16) * H + n0 + c4);   \
    bv3 = *(const float4*)(Wd + (size_t)((K0) + kr0 + 24) * H + n0 + c4);

    DN_LOADS(0);
    for (int k0 = 0; k0 < K; k0 += BK) {
        __syncthreads();
        *(uint4*)&Al[swz8(srow, tid & 3)] = av0;
        *(uint4*)&Al[swz8(srow + 64, tid & 3)] = av1;
        wr4(Bl, c4, kr0, bv0);
        wr4(Bl, c4, kr0 + 8, bv1);
        wr4(Bl, c4, kr0 + 16, bv2);
        wr4(Bl, c4, kr0 + 24, bv3);
        __syncthreads();
        if (k0 + BK < K) { DN_LOADS(k0 + BK); }   // prefetch overlaps MFMA
        bf16x8 af[4], bfr[4];
#pragma unroll
        for (int i = 0; i < 4; ++i) {
            af[i]  = *(const bf16x8*)&Al[swz8(wr * 64 + i * 16 + lrow, lkc)];
            bfr[i] = *(const bf16x8*)&Bl[swz8(wc * 64 + i * 16 + lrow, lkc)];
        }
#pragma unroll
        for (int i = 0; i < 4; ++i)
#pragma unroll
            for (int j = 0; j < 4; ++j)
                acc[i][j] = __builtin_amdgcn_mfma_f32_16x16x32_bf16(af[i], bfr[j], acc[i][j], 0, 0, 0);
    }
#undef DN_LOADS

    const int q4 = (lane >> 4) * 4;
    const int cc = lane & 15;
#pragma unroll
    for (int i = 0; i < 4; ++i) {
        const int rbase = m0 + wr * 64 + i * 16 + q4;
#pragma unroll
        for (int r = 0; r < 4; ++r) {
            const int row = rbase + r;
            if (SH) {
#pragma unroll
                for (int j = 0; j < 4; ++j) {
                    const int col = n0 + wc * 64 + j * 16 + cc;
                    atomicAdd(&OUT[(size_t)row * H + col], acc[i][j][r] + bd[col]);
                }
            } else if (row < ne) {
                const int tok = tok_id[(size_t)z * T + row];
                const float w = tok_w[(size_t)z * T + row];
#pragma unroll
                for (int j = 0; j < 4; ++j) {
                    const int col = n0 + wc * 64 + j * 16 + cc;
                    atomicAdd(&OUT[(size_t)tok * H + col], w * (acc[i][j][r] + bd[col]));
                }
            }
        }
    }
}

extern "C" void kernel_launch(void* const* d_in, const int* in_sizes, int n_in,
                              void* d_out, int out_size, void* d_ws, size_t ws_size,
                              hipStream_t stream)
{
    const float* X   = (const float*)d_in[0];
    const float* RW  = (const float*)d_in[1];
    const float* RB  = (const float*)d_in[2];
    const float* CB  = (const float*)d_in[3];
    const float* GWg = (const float*)d_in[4];
    const float* Gbg = (const float*)d_in[5];
    const float* GWu = (const float*)d_in[6];
    const float* Gbu = (const float*)d_in[7];
    const float* GWd = (const float*)d_in[8];
    const float* Gbd = (const float*)d_in[9];
    const float* SWg = (const float*)d_in[10];
    const float* Sbg = (const float*)d_in[11];
    const float* SWu = (const float*)d_in[12];
    const float* Sbu = (const float*)d_in[13];
    const float* SWd = (const float*)d_in[14];
    const float* Sbd = (const float*)d_in[15];
    float* OUT = (float*)d_out;
    const int T = in_sizes[0] / H;   // 2048

    // ---- workspace (~12.4 MB; 19.1 MB proven safe) ----
    char* w = (char*)d_ws;
    int* cnt     = (int*)w;            w += 256;
    int* offs    = (int*)w;            w += 256;
    int* sel     = (int*)w;            w += (size_t)T * TOPK * sizeof(int);
    float* selw  = (float*)w;          w += (size_t)T * TOPK * sizeof(float);
    int* tok_id  = (int*)w;            w += (size_t)E_NUM * T * sizeof(int);
    float* tok_w = (float*)w;          w += (size_t)E_NUM * T * sizeof(float);
    unsigned short* Xb  = (unsigned short*)w; w += (size_t)T * H * 2;
    unsigned short* HSs = (unsigned short*)w; w += (size_t)T * IS_DIM * 2;
    unsigned short* HBr = (unsigned short*)w; w += (size_t)T * TOPK * I_DIM * 2;

    // zero-init OUT (merged down kernel is all-atomic)
    hipMemsetAsync(OUT, 0, (size_t)out_size * sizeof(float), stream);

    // routing + fused activation convert
    router_score_k<<<T / 4, 256, 0, stream>>>(X, RW, RB, CB, sel, selw, Xb, T);
    build_lists_k<<<E_NUM, 256, 0, stream>>>(sel, selw, cnt, tok_id, tok_w, T);
    scan_k<<<1, 64, 0, stream>>>(cnt, offs);

    // merged gate+up: 1D XCD-swizzled grid = 8 * 16 * ceil(204/8) = 3328
    gateup_all_k<<<3328, 256, 0, stream>>>(
        Xb, GWg, GWu, Gbg, Gbu, SWg, SWu, Sbg, Sbu,
        cnt, offs, tok_id, HBr, HSs, T);

    // merged down (shared + routed, all-atomic): 8 * 16 * ceil(102/8) = 1664
    down_all_k<<<1664, 256, 0, stream>>>(
        HBr, HSs, GWd, Gbd, SWd, Sbd, cnt, offs, tok_id, tok_w, OUT, T);
}